// Round 1
// baseline (2148.998 us; speedup 1.0000x reference)
//
#include <hip/hip_runtime.h>
#include <math.h>

#define HH 480
#define WW 640
#define HWSZ (HH*WW)        // 307200
#define NPC 22432
#define IMG_SZ (128*HWSZ)   // 39321600
#define NBI 256             // gram img partial blocks
#define NBP 64              // gram pcd partial blocks
#define CHUNK_I 1200        // 256*1200 = 307200
#define CHUNK_P 351         // 64*351 = 22464 >= 22432

// ws float offsets
#define OFF_SUMS_IMG 0
#define OFF_SUMS_PCD 128
#define OFF_BIAS2    256
#define OFF_COV_IMG  512
#define OFF_COV_PCD  16896
#define OFF_INV_IMG  33280
#define OFF_INV_PCD  49664
#define OFF_MT_IMG   66048
#define OFF_MT_PCD   82432
#define OFF_LWT      98816
#define OFF_WT       115200       // 128*9*128 = 147456
#define OFF_PART_IMG 262656       // NBI*16384 = 4194304
#define OFF_PART_PCD 4456960      // NBP*16384 = 1048576
// end = 5505536 floats ~= 22 MB

// ---------------- prep: fold BN into conv weights, transpose linear weights ----
__global__ void prep_kernel(const float* __restrict__ conv_w, const float* __restrict__ conv_b,
                            const float* __restrict__ gamma, const float* __restrict__ beta,
                            const float* __restrict__ mean, const float* __restrict__ var,
                            const float* __restrict__ lin_w, float* __restrict__ ws) {
  int tid = blockIdx.x * blockDim.x + threadIdx.x;
  int nth = gridDim.x * blockDim.x;
  for (int oc = tid; oc < 128; oc += nth) {
    float s = gamma[oc] / sqrtf(var[oc] + 1e-5f);
    ws[OFF_BIAS2 + oc] = (conv_b[oc] - mean[oc]) * s + beta[oc];
  }
  // wT[ci][k][oc] = conv_w[oc][ci][k] * s[oc]
  for (int e = tid; e < 128*9*128; e += nth) {
    int oc = e & 127; int k = (e >> 7) % 9; int ci = e / 1152;
    float s = gamma[oc] / sqrtf(var[oc] + 1e-5f);
    ws[OFF_WT + e] = conv_w[(oc*128 + ci)*9 + k] * s;
  }
  // lwT[k][c] = lin_w[c][k]
  for (int e = tid; e < 128*128; e += nth) {
    int c2 = e & 127; int k = e >> 7;
    ws[OFF_LWT + e] = lin_w[c2*128 + k];
  }
}

// ---------------- conv 3x3 + fused BN + ReLU -> X (d_out img slab) -------------
__launch_bounds__(256)
__global__ void conv_kernel(const float* __restrict__ img,
                            const float* __restrict__ ws,
                            float* __restrict__ outX) {
  __shared__ __align__(16) float xs[8][10][20];
  __shared__ __align__(16) float wsm[8][9][64];
  const int b = blockIdx.x;
  const int oc0 = (b & 1) * 64;
  const int sidx = b >> 1;
  const int h0 = (sidx / 40) * 8;
  const int w0 = (sidx % 40) * 16;
  const int t = threadIdx.x;
  const int oc_t = t & 15;        // 16 groups of 4 oc
  const int px_t = t >> 4;        // 16 pixel tiles of 1x8
  const int ph = px_t >> 1;
  const int pw0 = (px_t & 1) * 8;
  float acc[4][8];
#pragma unroll
  for (int o = 0; o < 4; o++)
#pragma unroll
    for (int m = 0; m < 8; m++) acc[o][m] = 0.f;
  const float* wT = ws + OFF_WT;
  for (int ci0 = 0; ci0 < 128; ci0 += 8) {
    __syncthreads();
    for (int e = t; e < 1440; e += 256) {
      int ci = e / 180; int rem = e - ci*180; int r = rem / 18; int cc2 = rem - r*18;
      int gh = h0 + r - 1, gw = w0 + cc2 - 1;
      float v = 0.f;
      if ((unsigned)gh < (unsigned)HH && (unsigned)gw < (unsigned)WW)
        v = img[(ci0+ci)*HWSZ + gh*WW + gw];
      xs[ci][r][cc2] = v;
    }
    for (int e = t; e < 4608; e += 256) {
      int oc = e & 63; int k = (e >> 6) % 9; int ci = e / 576;
      wsm[ci][k][oc] = wT[((ci0+ci)*9 + k)*128 + oc0 + oc];
    }
    __syncthreads();
#pragma unroll
    for (int ci = 0; ci < 8; ci++) {
#pragma unroll
      for (int kh = 0; kh < 3; kh++) {
        float x10[10];
        float4 xa = *(const float4*)&xs[ci][ph+kh][pw0];
        float4 xb = *(const float4*)&xs[ci][ph+kh][pw0+4];
        x10[0]=xa.x; x10[1]=xa.y; x10[2]=xa.z; x10[3]=xa.w;
        x10[4]=xb.x; x10[5]=xb.y; x10[6]=xb.z; x10[7]=xb.w;
        x10[8]=xs[ci][ph+kh][pw0+8]; x10[9]=xs[ci][ph+kh][pw0+9];
#pragma unroll
        for (int kw = 0; kw < 3; kw++) {
          float4 wv = *(const float4*)&wsm[ci][kh*3+kw][oc_t*4];
#pragma unroll
          for (int m = 0; m < 8; m++) {
            float xv = x10[kw+m];
            acc[0][m] += wv.x*xv; acc[1][m] += wv.y*xv;
            acc[2][m] += wv.z*xv; acc[3][m] += wv.w*xv;
          }
        }
      }
    }
  }
#pragma unroll
  for (int o = 0; o < 4; o++) {
    int oc = oc0 + oc_t*4 + o;
    float bias = ws[OFF_BIAS2 + oc];
    float4 r0, r1;
    r0.x = fmaxf(acc[o][0]+bias, 0.f); r0.y = fmaxf(acc[o][1]+bias, 0.f);
    r0.z = fmaxf(acc[o][2]+bias, 0.f); r0.w = fmaxf(acc[o][3]+bias, 0.f);
    r1.x = fmaxf(acc[o][4]+bias, 0.f); r1.y = fmaxf(acc[o][5]+bias, 0.f);
    r1.z = fmaxf(acc[o][6]+bias, 0.f); r1.w = fmaxf(acc[o][7]+bias, 0.f);
    float* dst = outX + (size_t)oc*HWSZ + (h0+ph)*WW + w0 + pw0;
    *(float4*)dst = r0; *(float4*)(dst+4) = r1;
  }
}

// ---------------- linear + ReLU -> Z (d_out pcd slab) --------------------------
__launch_bounds__(256)
__global__ void linear_kernel(const float* __restrict__ pcd,
                              const float* __restrict__ ws,
                              const float* __restrict__ lin_b,
                              float* __restrict__ Z) {
  __shared__ __align__(16) float Mt[128][132];
  __shared__ __align__(16) float zs[16][132];
  const int b = blockIdx.x, t = threadIdx.x;
  const int n0 = b * 16;
#pragma unroll
  for (int i = 0; i < 16; i++) {
    int idx = t + i*256; int r = idx >> 5; int c4 = (idx & 31)*4;
    *(float4*)&Mt[r][c4] = *(const float4*)&ws[OFF_LWT + r*128 + c4];
  }
#pragma unroll
  for (int i = 0; i < 2; i++) {
    int idx = t + i*256; int r = idx >> 5; int c4 = (idx & 31)*4;
    *(float4*)&zs[r][c4] = *(const float4*)&pcd[(size_t)(n0+r)*128 + c4];
  }
  __syncthreads();
  const int nl = t & 15;
  const int c0 = (t >> 4) * 8;
  float acc[8];
#pragma unroll
  for (int q = 0; q < 8; q++) acc[q] = 0.f;
#pragma unroll 8
  for (int k = 0; k < 128; k++) {
    float z = zs[nl][k];
    float4 wa = *(const float4*)&Mt[k][c0];
    float4 wb = *(const float4*)&Mt[k][c0+4];
    acc[0]+=z*wa.x; acc[1]+=z*wa.y; acc[2]+=z*wa.z; acc[3]+=z*wa.w;
    acc[4]+=z*wb.x; acc[5]+=z*wb.y; acc[6]+=z*wb.z; acc[7]+=z*wb.w;
  }
  float4 ba = *(const float4*)&lin_b[c0];
  float4 bb = *(const float4*)&lin_b[c0+4];
  float4 r0, r1;
  r0.x = fmaxf(acc[0]+ba.x,0.f); r0.y = fmaxf(acc[1]+ba.y,0.f);
  r0.z = fmaxf(acc[2]+ba.z,0.f); r0.w = fmaxf(acc[3]+ba.w,0.f);
  r1.x = fmaxf(acc[4]+bb.x,0.f); r1.y = fmaxf(acc[5]+bb.y,0.f);
  r1.z = fmaxf(acc[6]+bb.z,0.f); r1.w = fmaxf(acc[7]+bb.w,0.f);
  float* dst = Z + (size_t)(n0+nl)*128 + c0;
  *(float4*)dst = r0; *(float4*)(dst+4) = r1;
}

// ---------------- channel sums ------------------------------------------------
__launch_bounds__(256)
__global__ void sums_img_kernel(const float* __restrict__ X, float* __restrict__ ws) {
  const int c = blockIdx.x, t = threadIdx.x;
  const float4* row = (const float4*)(X + (size_t)c*HWSZ);
  float s = 0.f;
  for (int i = t; i < HWSZ/4; i += 256) { float4 v = row[i]; s += v.x+v.y+v.z+v.w; }
  __shared__ float red[256];
  red[t] = s; __syncthreads();
  for (int s2 = 128; s2 > 0; s2 >>= 1) { if (t < s2) red[t] += red[t+s2]; __syncthreads(); }
  if (t == 0) ws[OFF_SUMS_IMG + c] = red[0];
}

__launch_bounds__(256)
__global__ void sums_pcd_kernel(const float* __restrict__ Z, float* __restrict__ ws) {
  const int c = blockIdx.x, t = threadIdx.x;
  float s = 0.f;
  for (int n = t; n < NPC; n += 256) s += Z[(size_t)n*128 + c];
  __shared__ float red[256];
  red[t] = s; __syncthreads();
  for (int s2 = 128; s2 > 0; s2 >>= 1) { if (t < s2) red[t] += red[t+s2]; __syncthreads(); }
  if (t == 0) ws[OFF_SUMS_PCD + c] = red[0];
}

// ---------------- gram partials (deterministic: per-block partial buffers) -----
__launch_bounds__(256)
__global__ void gram_img_kernel(const float* __restrict__ X, float* __restrict__ part) {
  __shared__ __align__(16) float xt[64][132];
  const int b = blockIdx.x, t = threadIdx.x;
  const int n0 = b * CHUNK_I;
  const int i0 = (t >> 4) * 8, j0 = (t & 15) * 8;
  float acc[8][8];
#pragma unroll
  for (int a = 0; a < 8; a++)
#pragma unroll
    for (int q = 0; q < 8; q++) acc[a][q] = 0.f;
  const int c = t >> 1, halfsel = t & 1;
  for (int tile = 0; tile < 19; tile++) {
    __syncthreads();
#pragma unroll
    for (int k = 0; k < 8; k++) {
      int j4 = halfsel*8 + k;
      int l = tile*64 + j4*4;
      float4 v = {0.f,0.f,0.f,0.f};
      if (l < CHUNK_I) v = *(const float4*)&X[(size_t)c*HWSZ + n0 + l];
      xt[j4*4+0][c] = v.x; xt[j4*4+1][c] = v.y; xt[j4*4+2][c] = v.z; xt[j4*4+3][c] = v.w;
    }
    __syncthreads();
#pragma unroll 4
    for (int n = 0; n < 64; n++) {
      float4 a0 = *(const float4*)&xt[n][i0];
      float4 a1 = *(const float4*)&xt[n][i0+4];
      float4 b0 = *(const float4*)&xt[n][j0];
      float4 b1 = *(const float4*)&xt[n][j0+4];
      float av[8] = {a0.x,a0.y,a0.z,a0.w,a1.x,a1.y,a1.z,a1.w};
      float bv[8] = {b0.x,b0.y,b0.z,b0.w,b1.x,b1.y,b1.z,b1.w};
#pragma unroll
      for (int a = 0; a < 8; a++)
#pragma unroll
        for (int q = 0; q < 8; q++) acc[a][q] += av[a]*bv[q];
    }
  }
  float* dst = part + (size_t)b*16384;
#pragma unroll
  for (int a = 0; a < 8; a++) {
    float4 w0v = {acc[a][0],acc[a][1],acc[a][2],acc[a][3]};
    float4 w1v = {acc[a][4],acc[a][5],acc[a][6],acc[a][7]};
    *(float4*)&dst[(i0+a)*128 + j0] = w0v;
    *(float4*)&dst[(i0+a)*128 + j0 + 4] = w1v;
  }
}

__launch_bounds__(256)
__global__ void gram_pcd_kernel(const float* __restrict__ Z, float* __restrict__ part) {
  __shared__ __align__(16) float zt[64][132];
  const int b = blockIdx.x, t = threadIdx.x;
  const int n0 = b * CHUNK_P;
  const int i0 = (t >> 4) * 8, j0 = (t & 15) * 8;
  float acc[8][8];
#pragma unroll
  for (int a = 0; a < 8; a++)
#pragma unroll
    for (int q = 0; q < 8; q++) acc[a][q] = 0.f;
  for (int tile = 0; tile < 6; tile++) {
    __syncthreads();
#pragma unroll
    for (int i = 0; i < 8; i++) {
      int idx = t + i*256; int r = idx >> 5; int c4 = (idx & 31)*4;
      int lrow = tile*64 + r;
      int n = n0 + lrow;
      float4 v = {0.f,0.f,0.f,0.f};
      if (lrow < CHUNK_P && n < NPC) v = *(const float4*)&Z[(size_t)n*128 + c4];
      *(float4*)&zt[r][c4] = v;
    }
    __syncthreads();
#pragma unroll 4
    for (int n = 0; n < 64; n++) {
      float4 a0 = *(const float4*)&zt[n][i0];
      float4 a1 = *(const float4*)&zt[n][i0+4];
      float4 b0 = *(const float4*)&zt[n][j0];
      float4 b1 = *(const float4*)&zt[n][j0+4];
      float av[8] = {a0.x,a0.y,a0.z,a0.w,a1.x,a1.y,a1.z,a1.w};
      float bv[8] = {b0.x,b0.y,b0.z,b0.w,b1.x,b1.y,b1.z,b1.w};
#pragma unroll
      for (int a = 0; a < 8; a++)
#pragma unroll
        for (int q = 0; q < 8; q++) acc[a][q] += av[a]*bv[q];
    }
  }
  float* dst = part + (size_t)b*16384;
#pragma unroll
  for (int a = 0; a < 8; a++) {
    float4 w0v = {acc[a][0],acc[a][1],acc[a][2],acc[a][3]};
    float4 w1v = {acc[a][4],acc[a][5],acc[a][6],acc[a][7]};
    *(float4*)&dst[(i0+a)*128 + j0] = w0v;
    *(float4*)&dst[(i0+a)*128 + j0 + 4] = w1v;
  }
}

// ---------------- reduce partials -> cov --------------------------------------
__launch_bounds__(128)
__global__ void reduce_cov_kernel(float* __restrict__ ws) {
  const int b = blockIdx.x, t = threadIdx.x;
  const bool isimg = (b < 128);
  const int i = isimg ? b : b - 128;
  const int nparts = isimg ? NBI : NBP;
  const float* part = ws + (isimg ? OFF_PART_IMG : OFF_PART_PCD);
  float g = 0.f;
  for (int p = 0; p < nparts; p++) g += part[(size_t)p*16384 + i*128 + t];
  float Si = ws[(isimg ? OFF_SUMS_IMG : OFF_SUMS_PCD) + i];
  float Sj = ws[(isimg ? OFF_SUMS_IMG : OFF_SUMS_PCD) + t];
  float n = isimg ? (float)HWSZ : (float)NPC;
  float cov = (g - Si*Sj/n) / (n - 1.f);
  ws[(isimg ? OFF_COV_IMG : OFF_COV_PCD) + i*128 + t] = cov;
}

// ---------------- in-place Gauss-Jordan inverse of (cov + 1e-6 I) --------------
__launch_bounds__(512)
__global__ void invert_kernel(float* __restrict__ ws) {
  __shared__ __align__(16) float A[128][132];
  const int b = blockIdx.x, t = threadIdx.x;
  const float* src = ws + (b == 0 ? OFF_COV_IMG : OFF_COV_PCD);
  float* dst = ws + (b == 0 ? OFF_INV_IMG : OFF_INV_PCD);
  for (int i = 0; i < 32; i++) {
    int idx = t + i*512; int r = idx >> 7; int cc = idx & 127;
    A[r][cc] = src[idx] + (r == cc ? 1e-6f : 0.f);
  }
  const int row = t >> 2;
  const int cbase = (t & 3) * 32;
  for (int k = 0; k < 128; k++) {
    __syncthreads();
    float ip = 1.f / A[k][k];
    float f = (row != k) ? A[row][k] : 0.f;
    __syncthreads();
    if (t < 128) A[k][t] = (t == k) ? ip : A[k][t] * ip;
    __syncthreads();
    if (row != k) {
#pragma unroll
      for (int cc = 0; cc < 8; cc++) {
        int c4 = cbase + cc*4;
        float4 v = *(const float4*)&A[row][c4];
        float4 p = *(const float4*)&A[k][c4];
        v.x -= f*p.x; v.y -= f*p.y; v.z -= f*p.z; v.w -= f*p.w;
        if (k >= c4 && k < c4+4) {
          float nv = -f*ip;
          if (k == c4) v.x = nv; else if (k == c4+1) v.y = nv;
          else if (k == c4+2) v.z = nv; else v.w = nv;
        }
        *(float4*)&A[row][c4] = v;
      }
    }
  }
  __syncthreads();
  for (int i = 0; i < 32; i++) {
    int idx = t + i*512; int r = idx >> 7; int cc = idx & 127;
    dst[idx] = A[r][cc];
  }
}

// ---------------- attention rows -> transposed mix matrices M^T ----------------
__launch_bounds__(128)
__global__ void attn_kernel(float* __restrict__ ws) {
  const int b = blockIdx.x, j = threadIdx.x;
  const bool isimg = (b < 128);
  const int i = isimg ? b : b - 128;
  // img: at_ip = softmax(cov_pcd @ inv_img /128); at_ii = softmax(cov_img @ cov_img^T /128)
  // pcd: at_pi = softmax(cov_img @ inv_pcd /128); at_pp = softmax(cov_pcd @ cov_pcd^T /128)
  const float* rowA = ws + (isimg ? OFF_COV_PCD : OFF_COV_IMG) + i*128;
  const float* matA = ws + (isimg ? OFF_INV_IMG : OFF_INV_PCD);
  const float* rowB = ws + (isimg ? OFF_COV_IMG : OFF_COV_PCD) + i*128;
  const float* matB = ws + (isimg ? OFF_COV_IMG : OFF_COV_PCD);
  __shared__ float rA[128], rB[128], red[128];
  rA[j] = rowA[j]; rB[j] = rowB[j];
  __syncthreads();
  float dA = 0.f, dB = 0.f;
#pragma unroll 8
  for (int k = 0; k < 128; k += 4) {
    float4 va = *(const float4*)&matA[j*128 + k];
    float4 vb = *(const float4*)&matB[j*128 + k];
    dA += rA[k]*va.x + rA[k+1]*va.y + rA[k+2]*va.z + rA[k+3]*va.w;
    dB += rB[k]*vb.x + rB[k+1]*vb.y + rB[k+2]*vb.z + rB[k+3]*vb.w;
  }
  dA *= 0.0078125f; dB *= 0.0078125f;
  // softmax over j for dA
  red[j] = dA; __syncthreads();
  for (int s2 = 64; s2 > 0; s2 >>= 1) { if (j < s2) red[j] = fmaxf(red[j], red[j+s2]); __syncthreads(); }
  float mA = red[0]; __syncthreads();
  float eA = expf(dA - mA);
  red[j] = eA; __syncthreads();
  for (int s2 = 64; s2 > 0; s2 >>= 1) { if (j < s2) red[j] += red[j+s2]; __syncthreads(); }
  float sA = red[0]; __syncthreads();
  // softmax over j for dB
  red[j] = dB; __syncthreads();
  for (int s2 = 64; s2 > 0; s2 >>= 1) { if (j < s2) red[j] = fmaxf(red[j], red[j+s2]); __syncthreads(); }
  float mB = red[0]; __syncthreads();
  float eB = expf(dB - mB);
  red[j] = eB; __syncthreads();
  for (int s2 = 64; s2 > 0; s2 >>= 1) { if (j < s2) red[j] += red[j+s2]; __syncthreads(); }
  float sB = red[0]; __syncthreads();
  float m = 0.1f * (eA/sA + eB/sB);   // 0.5 * TAU * (atA + atB)
  float* MT = ws + (isimg ? OFF_MT_IMG : OFF_MT_PCD);
  MT[j*128 + i] = m;                  // store transposed: MT[k][c] = M[c][k]
}

// ---------------- img final: io = M_img @ io + 0.8*img (in place, per 128-col slab)
__launch_bounds__(512)
__global__ void img_final_kernel(const float* __restrict__ img_in,
                                 const float* __restrict__ ws,
                                 float* __restrict__ io) {
  __shared__ __align__(16) float ts[128][128];
  const int b = blockIdx.x, t = threadIdx.x;
  const int n0 = b * 128;
#pragma unroll
  for (int i = 0; i < 8; i++) {
    int idx = t + i*512; int r = idx >> 5; int c4 = (idx & 31)*4;
    *(float4*)&ts[r][c4] = *(const float4*)&io[(size_t)r*HWSZ + n0 + c4];
  }
  __syncthreads();
  const int c0 = (t >> 5) * 8;
  const int nn0 = (t & 31) * 4;
  const float* Mt = ws + OFF_MT_IMG;
  float acc[8][4];
#pragma unroll
  for (int a = 0; a < 8; a++)
#pragma unroll
    for (int q = 0; q < 4; q++) acc[a][q] = 0.f;
#pragma unroll 4
  for (int k = 0; k < 128; k++) {
    float4 x = *(const float4*)&ts[k][nn0];
    float4 m0 = *(const float4*)&Mt[k*128 + c0];
    float4 m1 = *(const float4*)&Mt[k*128 + c0 + 4];
    float mv[8] = {m0.x,m0.y,m0.z,m0.w,m1.x,m1.y,m1.z,m1.w};
    float xv[4] = {x.x,x.y,x.z,x.w};
#pragma unroll
    for (int a = 0; a < 8; a++)
#pragma unroll
      for (int q = 0; q < 4; q++) acc[a][q] += mv[a]*xv[q];
  }
#pragma unroll
  for (int a = 0; a < 8; a++) {
    size_t off = (size_t)(c0+a)*HWSZ + n0 + nn0;
    float4 orig = *(const float4*)&img_in[off];
    float4 r;
    r.x = acc[a][0] + 0.8f*orig.x;
    r.y = acc[a][1] + 0.8f*orig.y;
    r.z = acc[a][2] + 0.8f*orig.z;
    r.w = acc[a][3] + 0.8f*orig.w;
    *(float4*)&io[off] = r;
  }
}

// ---------------- pcd final: Z = Z @ M_pcd^T + 0.8*pcd (in place, per 16-row slab)
__launch_bounds__(256)
__global__ void pcd_final_kernel(const float* __restrict__ pcd_in,
                                 const float* __restrict__ ws,
                                 float* __restrict__ Z) {
  __shared__ __align__(16) float Mt[128][132];
  __shared__ __align__(16) float zs[16][132];
  const int b = blockIdx.x, t = threadIdx.x;
  const int n0 = b * 16;
#pragma unroll
  for (int i = 0; i < 16; i++) {
    int idx = t + i*256; int r = idx >> 5; int c4 = (idx & 31)*4;
    *(float4*)&Mt[r][c4] = *(const float4*)&ws[OFF_MT_PCD + r*128 + c4];
  }
#pragma unroll
  for (int i = 0; i < 2; i++) {
    int idx = t + i*256; int r = idx >> 5; int c4 = (idx & 31)*4;
    *(float4*)&zs[r][c4] = *(const float4*)&Z[(size_t)(n0+r)*128 + c4];
  }
  __syncthreads();
  const int nl = t & 15;
  const int c0 = (t >> 4) * 8;
  float acc[8];
#pragma unroll
  for (int q = 0; q < 8; q++) acc[q] = 0.f;
#pragma unroll 8
  for (int k = 0; k < 128; k++) {
    float z = zs[nl][k];
    float4 wa = *(const float4*)&Mt[k][c0];
    float4 wb = *(const float4*)&Mt[k][c0+4];
    acc[0]+=z*wa.x; acc[1]+=z*wa.y; acc[2]+=z*wa.z; acc[3]+=z*wa.w;
    acc[4]+=z*wb.x; acc[5]+=z*wb.y; acc[6]+=z*wb.z; acc[7]+=z*wb.w;
  }
  size_t off = (size_t)(n0+nl)*128 + c0;
  float4 pa = *(const float4*)&pcd_in[off];
  float4 pb = *(const float4*)&pcd_in[off+4];
  float4 r0, r1;
  r0.x = acc[0] + 0.8f*pa.x; r0.y = acc[1] + 0.8f*pa.y;
  r0.z = acc[2] + 0.8f*pa.z; r0.w = acc[3] + 0.8f*pa.w;
  r1.x = acc[4] + 0.8f*pb.x; r1.y = acc[5] + 0.8f*pb.y;
  r1.z = acc[6] + 0.8f*pb.z; r1.w = acc[7] + 0.8f*pb.w;
  *(float4*)&Z[off] = r0; *(float4*)&Z[off+4] = r1;
}

extern "C" void kernel_launch(void* const* d_in, const int* in_sizes, int n_in,
                              void* d_out, int out_size, void* d_ws, size_t ws_size,
                              hipStream_t stream) {
  (void)in_sizes; (void)n_in; (void)out_size; (void)ws_size;
  const float* img_in = (const float*)d_in[0];
  const float* pcd_in = (const float*)d_in[1];
  const float* conv_w = (const float*)d_in[2];
  const float* conv_b = (const float*)d_in[3];
  const float* gamma  = (const float*)d_in[4];
  const float* beta   = (const float*)d_in[5];
  const float* mean   = (const float*)d_in[6];
  const float* var    = (const float*)d_in[7];
  const float* lin_w  = (const float*)d_in[8];
  const float* lin_b  = (const float*)d_in[9];
  float* out = (float*)d_out;
  float* X = out;            // [128][307200] staged conv output, transformed in place
  float* Z = out + IMG_SZ;   // [22432][128] staged linear output, transformed in place
  float* ws = (float*)d_ws;

  hipLaunchKernelGGL(prep_kernel, dim3(64), dim3(256), 0, stream,
                     conv_w, conv_b, gamma, beta, mean, var, lin_w, ws);
  hipLaunchKernelGGL(conv_kernel, dim3(4800), dim3(256), 0, stream, img_in, ws, X);
  hipLaunchKernelGGL(linear_kernel, dim3(NPC/16), dim3(256), 0, stream, pcd_in, ws, lin_b, Z);
  hipLaunchKernelGGL(sums_img_kernel, dim3(128), dim3(256), 0, stream, X, ws);
  hipLaunchKernelGGL(sums_pcd_kernel, dim3(128), dim3(256), 0, stream, Z, ws);
  hipLaunchKernelGGL(gram_img_kernel, dim3(NBI), dim3(256), 0, stream, X, ws + OFF_PART_IMG);
  hipLaunchKernelGGL(gram_pcd_kernel, dim3(NBP), dim3(256), 0, stream, Z, ws + OFF_PART_PCD);
  hipLaunchKernelGGL(reduce_cov_kernel, dim3(256), dim3(128), 0, stream, ws);
  hipLaunchKernelGGL(invert_kernel, dim3(2), dim3(512), 0, stream, ws);
  hipLaunchKernelGGL(attn_kernel, dim3(256), dim3(128), 0, stream, ws);
  hipLaunchKernelGGL(img_final_kernel, dim3(HWSZ/128), dim3(512), 0, stream, img_in, ws, X);
  hipLaunchKernelGGL(pcd_final_kernel, dim3(NPC/16), dim3(256), 0, stream, pcd_in, ws, Z);
}

// Round 2
// 1241.205 us; speedup vs baseline: 1.7314x; 1.7314x over previous
//
#include <hip/hip_runtime.h>
#include <math.h>

#define HH 480
#define WW 640
#define HWSZ (HH*WW)        // 307200
#define NPC 22432
#define IMG_SZ (128*HWSZ)   // 39321600
#define NBI 256             // gram img partial blocks
#define NBP 64              // gram pcd partial blocks
#define CHUNK_I 1200        // 256*1200 = 307200
#define CHUNK_P 351         // 64*351 = 22464 >= 22432

typedef unsigned short u16;
typedef unsigned int u32;
typedef __attribute__((ext_vector_type(8))) short bf16x8;
typedef __attribute__((ext_vector_type(4))) float f32x4;

// ws float offsets
#define OFF_SUMS_IMG 0
#define OFF_SUMS_PCD 128
#define OFF_BIAS2    256
#define OFF_COV_IMG  512
#define OFF_COV_PCD  16896
#define OFF_INV_IMG  33280
#define OFF_INV_PCD  49664
#define OFF_MT_IMG   66048
#define OFF_MT_PCD   82432
#define OFF_LWT      98816
#define OFF_WT       115200       // 128*9*128 fp32
#define OFF_PART_IMG 262656       // NBI*16384
#define OFF_PART_PCD 4456960      // NBP*16384
#define OFF_WB       5505536      // 9*128*128 bf16 = 73728 floats
#define OFF_TIMG_F   5579264      // 482*642*128 bf16 = 19804416 floats
#define TIMG_PAD_W 642
#define TIMG_PX (482*642)         // 309444
#define TIMG_U16 (TIMG_PX*128)    // 39608832
#define WS_NEED_FLOATS 25383680   // OFF_TIMG_F + TIMG_U16/2

__device__ inline u32 pack_bf16(float a, float b) {
  u32 ua = __float_as_uint(a), ub = __float_as_uint(b);
  ua += 0x7FFFu + ((ua >> 16) & 1u);
  ub += 0x7FFFu + ((ub >> 16) & 1u);
  return (ua >> 16) | (ub & 0xFFFF0000u);
}

// ---------------- prep: fold BN into conv weights, transpose linear weights ----
__global__ void prep_kernel(const float* __restrict__ conv_w, const float* __restrict__ conv_b,
                            const float* __restrict__ gamma, const float* __restrict__ beta,
                            const float* __restrict__ mean, const float* __restrict__ var,
                            const float* __restrict__ lin_w, float* __restrict__ ws, int big) {
  int tid = blockIdx.x * blockDim.x + threadIdx.x;
  int nth = gridDim.x * blockDim.x;
  for (int oc = tid; oc < 128; oc += nth) {
    float s = gamma[oc] / sqrtf(var[oc] + 1e-5f);
    ws[OFF_BIAS2 + oc] = (conv_b[oc] - mean[oc]) * s + beta[oc];
  }
  if (big) {
    // Wb bf16 [tap][oc][ci]
    u16* Wb = (u16*)(ws + OFF_WB);
    for (int e = tid; e < 9*128*128; e += nth) {
      int ci = e & 127; int oc = (e >> 7) & 127; int tap = e >> 14;
      float s = gamma[oc] / sqrtf(var[oc] + 1e-5f);
      float v = conv_w[(oc*128 + ci)*9 + tap] * s;
      u32 u = __float_as_uint(v); u += 0x7FFFu + ((u >> 16) & 1u);
      Wb[e] = (u16)(u >> 16);
    }
  } else {
    // fp32 wT[ci][k][oc] = conv_w[oc][ci][k] * s[oc]
    for (int e = tid; e < 128*9*128; e += nth) {
      int oc = e & 127; int k = (e >> 7) % 9; int ci = e / 1152;
      float s = gamma[oc] / sqrtf(var[oc] + 1e-5f);
      ws[OFF_WT + e] = conv_w[(oc*128 + ci)*9 + k] * s;
    }
  }
  // lwT[k][c] = lin_w[c][k]
  for (int e = tid; e < 128*128; e += nth) {
    int c2 = e & 127; int k = e >> 7;
    ws[OFF_LWT + e] = lin_w[c2*128 + k];
  }
}

// ---------------- zero-fill Timg (border safety) -------------------------------
__global__ void timg_zero_kernel(uint4* __restrict__ p, int n) {
  int i = blockIdx.x * blockDim.x + threadIdx.x;
  if (i < n) p[i] = make_uint4(0u, 0u, 0u, 0u);
}

// ---------------- img fp32 [128][480][640] -> Timg bf16 padded [482*642][128] --
__launch_bounds__(256)
__global__ void timg_kernel(const float* __restrict__ img, u16* __restrict__ Timg) {
  __shared__ float xt[64][133];
  const int b = blockIdx.x;
  const int h = b / 10, w0 = (b % 10) * 64;
  const int t = threadIdx.x;
  const int wl = t & 63, cib = t >> 6;
#pragma unroll
  for (int i = 0; i < 32; ++i) {
    int ci = cib + i*4;
    xt[wl][ci] = img[(size_t)ci*HWSZ + h*WW + w0 + wl];
  }
  __syncthreads();
  const int wp = t >> 2, c0 = (t & 3) * 32;
  u32 out[16];
#pragma unroll
  for (int j = 0; j < 16; ++j) {
    float a = xt[wp][c0 + 2*j], bb = xt[wp][c0 + 2*j + 1];
    out[j] = pack_bf16(a, bb);
  }
  u16* dst = Timg + ((size_t)(h+1)*TIMG_PAD_W + (w0 + 1 + wp)) * 128 + c0;
#pragma unroll
  for (int q = 0; q < 4; ++q)
    *(uint4*)(dst + q*8) = make_uint4(out[q*4], out[q*4+1], out[q*4+2], out[q*4+3]);
}

// ---------------- conv via 9-tap implicit GEMM, bf16 MFMA ----------------------
// block: 128 oc x 256 px (4 rows x 64 w), 4 waves split along rows
__launch_bounds__(256)
__global__ void conv_mfma_kernel(const u16* __restrict__ Timg,
                                 const u16* __restrict__ Wb,
                                 const float* __restrict__ ws,
                                 float* __restrict__ X) {
  const int b = blockIdx.x;
  const int h0 = (b / 10) * 4;
  const int w0 = (b % 10) * 64;
  const int t = threadIdx.x;
  const int wv = t >> 6;          // wave id = row within tile
  const int l = t & 63;
  const int n_lane = l & 15;
  const int k_lane = l >> 4;
  const int px_center = (h0 + wv + 1) * TIMG_PAD_W + (w0 + 1) + n_lane;

  f32x4 acc[8][4];
#pragma unroll
  for (int mt = 0; mt < 8; ++mt)
#pragma unroll
    for (int nt = 0; nt < 4; ++nt) acc[mt][nt] = (f32x4){0.f,0.f,0.f,0.f};

  const int toff[9] = {-TIMG_PAD_W-1, -TIMG_PAD_W, -TIMG_PAD_W+1,
                       -1, 0, 1,
                       TIMG_PAD_W-1, TIMG_PAD_W, TIMG_PAD_W+1};
  const u16* ab0 = Wb + n_lane*128 + k_lane*8;
#pragma unroll 1
  for (int tap = 0; tap < 9; ++tap) {
    const u16* bb = Timg + (size_t)(px_center + toff[tap]) * 128 + k_lane*8;
    const u16* ab = ab0 + tap*16384;
#pragma unroll
    for (int ci0 = 0; ci0 < 128; ci0 += 32) {
      bf16x8 Bf[4], Af[8];
#pragma unroll
      for (int nt = 0; nt < 4; ++nt) Bf[nt] = *(const bf16x8*)(bb + nt*2048 + ci0);
#pragma unroll
      for (int mt = 0; mt < 8; ++mt) Af[mt] = *(const bf16x8*)(ab + mt*2048 + ci0);
#pragma unroll
      for (int mt = 0; mt < 8; ++mt)
#pragma unroll
        for (int nt = 0; nt < 4; ++nt)
          acc[mt][nt] = __builtin_amdgcn_mfma_f32_16x16x32_bf16(Af[mt], Bf[nt], acc[mt][nt], 0, 0, 0);
    }
  }
  // epilogue: bias + ReLU, D layout col=lane&15 (px), row=(lane>>4)*4+reg (oc)
  const float* bias = ws + OFF_BIAS2;
  const int pxw = (h0 + wv) * WW + w0 + n_lane;
#pragma unroll
  for (int mt = 0; mt < 8; ++mt) {
    f32x4 bv = *(const f32x4*)(bias + mt*16 + k_lane*4);
#pragma unroll
    for (int nt = 0; nt < 4; ++nt) {
#pragma unroll
      for (int r = 0; r < 4; ++r) {
        int oc = mt*16 + k_lane*4 + r;
        float v = acc[mt][nt][r] + bv[r];
        X[(size_t)oc*HWSZ + pxw + nt*16] = fmaxf(v, 0.f);
      }
    }
  }
}

// ---------------- fp32 fallback conv (round-1 kernel) --------------------------
__launch_bounds__(256)
__global__ void conv_kernel(const float* __restrict__ img,
                            const float* __restrict__ ws,
                            float* __restrict__ outX) {
  __shared__ __align__(16) float xs[8][10][20];
  __shared__ __align__(16) float wsm[8][9][64];
  const int b = blockIdx.x;
  const int oc0 = (b & 1) * 64;
  const int sidx = b >> 1;
  const int h0 = (sidx / 40) * 8;
  const int w0 = (sidx % 40) * 16;
  const int t = threadIdx.x;
  const int oc_t = t & 15;
  const int px_t = t >> 4;
  const int ph = px_t >> 1;
  const int pw0 = (px_t & 1) * 8;
  float acc[4][8];
#pragma unroll
  for (int o = 0; o < 4; o++)
#pragma unroll
    for (int m = 0; m < 8; m++) acc[o][m] = 0.f;
  const float* wT = ws + OFF_WT;
  for (int ci0 = 0; ci0 < 128; ci0 += 8) {
    __syncthreads();
    for (int e = t; e < 1440; e += 256) {
      int ci = e / 180; int rem = e - ci*180; int r = rem / 18; int cc2 = rem - r*18;
      int gh = h0 + r - 1, gw = w0 + cc2 - 1;
      float v = 0.f;
      if ((unsigned)gh < (unsigned)HH && (unsigned)gw < (unsigned)WW)
        v = img[(ci0+ci)*HWSZ + gh*WW + gw];
      xs[ci][r][cc2] = v;
    }
    for (int e = t; e < 4608; e += 256) {
      int oc = e & 63; int k = (e >> 6) % 9; int ci = e / 576;
      wsm[ci][k][oc] = wT[((ci0+ci)*9 + k)*128 + oc0 + oc];
    }
    __syncthreads();
#pragma unroll
    for (int ci = 0; ci < 8; ci++) {
#pragma unroll
      for (int kh = 0; kh < 3; kh++) {
        float x10[10];
        float4 xa = *(const float4*)&xs[ci][ph+kh][pw0];
        float4 xb = *(const float4*)&xs[ci][ph+kh][pw0+4];
        x10[0]=xa.x; x10[1]=xa.y; x10[2]=xa.z; x10[3]=xa.w;
        x10[4]=xb.x; x10[5]=xb.y; x10[6]=xb.z; x10[7]=xb.w;
        x10[8]=xs[ci][ph+kh][pw0+8]; x10[9]=xs[ci][ph+kh][pw0+9];
#pragma unroll
        for (int kw = 0; kw < 3; kw++) {
          float4 wv = *(const float4*)&wsm[ci][kh*3+kw][oc_t*4];
#pragma unroll
          for (int m = 0; m < 8; m++) {
            float xv = x10[kw+m];
            acc[0][m] += wv.x*xv; acc[1][m] += wv.y*xv;
            acc[2][m] += wv.z*xv; acc[3][m] += wv.w*xv;
          }
        }
      }
    }
  }
#pragma unroll
  for (int o = 0; o < 4; o++) {
    int oc = oc0 + oc_t*4 + o;
    float bias = ws[OFF_BIAS2 + oc];
    float4 r0, r1;
    r0.x = fmaxf(acc[o][0]+bias, 0.f); r0.y = fmaxf(acc[o][1]+bias, 0.f);
    r0.z = fmaxf(acc[o][2]+bias, 0.f); r0.w = fmaxf(acc[o][3]+bias, 0.f);
    r1.x = fmaxf(acc[o][4]+bias, 0.f); r1.y = fmaxf(acc[o][5]+bias, 0.f);
    r1.z = fmaxf(acc[o][6]+bias, 0.f); r1.w = fmaxf(acc[o][7]+bias, 0.f);
    float* dst = outX + (size_t)oc*HWSZ + (h0+ph)*WW + w0 + pw0;
    *(float4*)dst = r0; *(float4*)(dst+4) = r1;
  }
}

// ---------------- linear + ReLU -> Z (d_out pcd slab) --------------------------
__launch_bounds__(256)
__global__ void linear_kernel(const float* __restrict__ pcd,
                              const float* __restrict__ ws,
                              const float* __restrict__ lin_b,
                              float* __restrict__ Z) {
  __shared__ __align__(16) float Mt[128][132];
  __shared__ __align__(16) float zs[16][132];
  const int b = blockIdx.x, t = threadIdx.x;
  const int n0 = b * 16;
#pragma unroll
  for (int i = 0; i < 16; i++) {
    int idx = t + i*256; int r = idx >> 5; int c4 = (idx & 31)*4;
    *(float4*)&Mt[r][c4] = *(const float4*)&ws[OFF_LWT + r*128 + c4];
  }
#pragma unroll
  for (int i = 0; i < 2; i++) {
    int idx = t + i*256; int r = idx >> 5; int c4 = (idx & 31)*4;
    *(float4*)&zs[r][c4] = *(const float4*)&pcd[(size_t)(n0+r)*128 + c4];
  }
  __syncthreads();
  const int nl = t & 15;
  const int c0 = (t >> 4) * 8;
  float acc[8];
#pragma unroll
  for (int q = 0; q < 8; q++) acc[q] = 0.f;
#pragma unroll 8
  for (int k = 0; k < 128; k++) {
    float z = zs[nl][k];
    float4 wa = *(const float4*)&Mt[k][c0];
    float4 wb = *(const float4*)&Mt[k][c0+4];
    acc[0]+=z*wa.x; acc[1]+=z*wa.y; acc[2]+=z*wa.z; acc[3]+=z*wa.w;
    acc[4]+=z*wb.x; acc[5]+=z*wb.y; acc[6]+=z*wb.z; acc[7]+=z*wb.w;
  }
  float4 ba = *(const float4*)&lin_b[c0];
  float4 bb = *(const float4*)&lin_b[c0+4];
  float4 r0, r1;
  r0.x = fmaxf(acc[0]+ba.x,0.f); r0.y = fmaxf(acc[1]+ba.y,0.f);
  r0.z = fmaxf(acc[2]+ba.z,0.f); r0.w = fmaxf(acc[3]+ba.w,0.f);
  r1.x = fmaxf(acc[4]+bb.x,0.f); r1.y = fmaxf(acc[5]+bb.y,0.f);
  r1.z = fmaxf(acc[6]+bb.z,0.f); r1.w = fmaxf(acc[7]+bb.w,0.f);
  float* dst = Z + (size_t)(n0+nl)*128 + c0;
  *(float4*)dst = r0; *(float4*)(dst+4) = r1;
}

// ---------------- channel sums ------------------------------------------------
__launch_bounds__(256)
__global__ void sums_img_kernel(const float* __restrict__ X, float* __restrict__ ws) {
  const int c = blockIdx.x, t = threadIdx.x;
  const float4* row = (const float4*)(X + (size_t)c*HWSZ);
  float s = 0.f;
  for (int i = t; i < HWSZ/4; i += 256) { float4 v = row[i]; s += v.x+v.y+v.z+v.w; }
  __shared__ float red[256];
  red[t] = s; __syncthreads();
  for (int s2 = 128; s2 > 0; s2 >>= 1) { if (t < s2) red[t] += red[t+s2]; __syncthreads(); }
  if (t == 0) ws[OFF_SUMS_IMG + c] = red[0];
}

__launch_bounds__(256)
__global__ void sums_pcd_kernel(const float* __restrict__ Z, float* __restrict__ ws) {
  const int c = blockIdx.x, t = threadIdx.x;
  float s = 0.f;
  for (int n = t; n < NPC; n += 256) s += Z[(size_t)n*128 + c];
  __shared__ float red[256];
  red[t] = s; __syncthreads();
  for (int s2 = 128; s2 > 0; s2 >>= 1) { if (t < s2) red[t] += red[t+s2]; __syncthreads(); }
  if (t == 0) ws[OFF_SUMS_PCD + c] = red[0];
}

// ---------------- gram partials (deterministic: per-block partial buffers) -----
__launch_bounds__(256)
__global__ void gram_img_kernel(const float* __restrict__ X, float* __restrict__ part) {
  __shared__ __align__(16) float xt[64][132];
  const int b = blockIdx.x, t = threadIdx.x;
  const int n0 = b * CHUNK_I;
  const int i0 = (t >> 4) * 8, j0 = (t & 15) * 8;
  float acc[8][8];
#pragma unroll
  for (int a = 0; a < 8; a++)
#pragma unroll
    for (int q = 0; q < 8; q++) acc[a][q] = 0.f;
  const int c = t >> 1, halfsel = t & 1;
  for (int tile = 0; tile < 19; tile++) {
    __syncthreads();
#pragma unroll
    for (int k = 0; k < 8; k++) {
      int j4 = halfsel*8 + k;
      int l = tile*64 + j4*4;
      float4 v = {0.f,0.f,0.f,0.f};
      if (l < CHUNK_I) v = *(const float4*)&X[(size_t)c*HWSZ + n0 + l];
      xt[j4*4+0][c] = v.x; xt[j4*4+1][c] = v.y; xt[j4*4+2][c] = v.z; xt[j4*4+3][c] = v.w;
    }
    __syncthreads();
#pragma unroll 4
    for (int n = 0; n < 64; n++) {
      float4 a0 = *(const float4*)&xt[n][i0];
      float4 a1 = *(const float4*)&xt[n][i0+4];
      float4 b0 = *(const float4*)&xt[n][j0];
      float4 b1 = *(const float4*)&xt[n][j0+4];
      float av[8] = {a0.x,a0.y,a0.z,a0.w,a1.x,a1.y,a1.z,a1.w};
      float bv[8] = {b0.x,b0.y,b0.z,b0.w,b1.x,b1.y,b1.z,b1.w};
#pragma unroll
      for (int a = 0; a < 8; a++)
#pragma unroll
        for (int q = 0; q < 8; q++) acc[a][q] += av[a]*bv[q];
    }
  }
  float* dst = part + (size_t)b*16384;
#pragma unroll
  for (int a = 0; a < 8; a++) {
    float4 w0v = {acc[a][0],acc[a][1],acc[a][2],acc[a][3]};
    float4 w1v = {acc[a][4],acc[a][5],acc[a][6],acc[a][7]};
    *(float4*)&dst[(i0+a)*128 + j0] = w0v;
    *(float4*)&dst[(i0+a)*128 + j0 + 4] = w1v;
  }
}

__launch_bounds__(256)
__global__ void gram_pcd_kernel(const float* __restrict__ Z, float* __restrict__ part) {
  __shared__ __align__(16) float zt[64][132];
  const int b = blockIdx.x, t = threadIdx.x;
  const int n0 = b * CHUNK_P;
  const int i0 = (t >> 4) * 8, j0 = (t & 15) * 8;
  float acc[8][8];
#pragma unroll
  for (int a = 0; a < 8; a++)
#pragma unroll
    for (int q = 0; q < 8; q++) acc[a][q] = 0.f;
  for (int tile = 0; tile < 6; tile++) {
    __syncthreads();
#pragma unroll
    for (int i = 0; i < 8; i++) {
      int idx = t + i*256; int r = idx >> 5; int c4 = (idx & 31)*4;
      int lrow = tile*64 + r;
      int n = n0 + lrow;
      float4 v = {0.f,0.f,0.f,0.f};
      if (lrow < CHUNK_P && n < NPC) v = *(const float4*)&Z[(size_t)n*128 + c4];
      *(float4*)&zt[r][c4] = v;
    }
    __syncthreads();
#pragma unroll 4
    for (int n = 0; n < 64; n++) {
      float4 a0 = *(const float4*)&zt[n][i0];
      float4 a1 = *(const float4*)&zt[n][i0+4];
      float4 b0 = *(const float4*)&zt[n][j0];
      float4 b1 = *(const float4*)&zt[n][j0+4];
      float av[8] = {a0.x,a0.y,a0.z,a0.w,a1.x,a1.y,a1.z,a1.w};
      float bv[8] = {b0.x,b0.y,b0.z,b0.w,b1.x,b1.y,b1.z,b1.w};
#pragma unroll
      for (int a = 0; a < 8; a++)
#pragma unroll
        for (int q = 0; q < 8; q++) acc[a][q] += av[a]*bv[q];
    }
  }
  float* dst = part + (size_t)b*16384;
#pragma unroll
  for (int a = 0; a < 8; a++) {
    float4 w0v = {acc[a][0],acc[a][1],acc[a][2],acc[a][3]};
    float4 w1v = {acc[a][4],acc[a][5],acc[a][6],acc[a][7]};
    *(float4*)&dst[(i0+a)*128 + j0] = w0v;
    *(float4*)&dst[(i0+a)*128 + j0 + 4] = w1v;
  }
}

// ---------------- reduce partials -> cov --------------------------------------
__launch_bounds__(128)
__global__ void reduce_cov_kernel(float* __restrict__ ws) {
  const int b = blockIdx.x, t = threadIdx.x;
  const bool isimg = (b < 128);
  const int i = isimg ? b : b - 128;
  const int nparts = isimg ? NBI : NBP;
  const float* part = ws + (isimg ? OFF_PART_IMG : OFF_PART_PCD);
  float g = 0.f;
  for (int p = 0; p < nparts; p++) g += part[(size_t)p*16384 + i*128 + t];
  float Si = ws[(isimg ? OFF_SUMS_IMG : OFF_SUMS_PCD) + i];
  float Sj = ws[(isimg ? OFF_SUMS_IMG : OFF_SUMS_PCD) + t];
  float n = isimg ? (float)HWSZ : (float)NPC;
  float cov = (g - Si*Sj/n) / (n - 1.f);
  ws[(isimg ? OFF_COV_IMG : OFF_COV_PCD) + i*128 + t] = cov;
}

// ---------------- in-place Gauss-Jordan inverse of (cov + 1e-6 I) --------------
__launch_bounds__(512)
__global__ void invert_kernel(float* __restrict__ ws) {
  __shared__ __align__(16) float A[128][132];
  const int b = blockIdx.x, t = threadIdx.x;
  const float* src = ws + (b == 0 ? OFF_COV_IMG : OFF_COV_PCD);
  float* dst = ws + (b == 0 ? OFF_INV_IMG : OFF_INV_PCD);
  for (int i = 0; i < 32; i++) {
    int idx = t + i*512; int r = idx >> 7; int cc = idx & 127;
    A[r][cc] = src[idx] + (r == cc ? 1e-6f : 0.f);
  }
  const int row = t >> 2;
  const int cbase = (t & 3) * 32;
  for (int k = 0; k < 128; k++) {
    __syncthreads();
    float ip = 1.f / A[k][k];
    float f = (row != k) ? A[row][k] : 0.f;
    __syncthreads();
    if (t < 128) A[k][t] = (t == k) ? ip : A[k][t] * ip;
    __syncthreads();
    if (row != k) {
#pragma unroll
      for (int cc = 0; cc < 8; cc++) {
        int c4 = cbase + cc*4;
        float4 v = *(const float4*)&A[row][c4];
        float4 p = *(const float4*)&A[k][c4];
        v.x -= f*p.x; v.y -= f*p.y; v.z -= f*p.z; v.w -= f*p.w;
        if (k >= c4 && k < c4+4) {
          float nv = -f*ip;
          if (k == c4) v.x = nv; else if (k == c4+1) v.y = nv;
          else if (k == c4+2) v.z = nv; else v.w = nv;
        }
        *(float4*)&A[row][c4] = v;
      }
    }
  }
  __syncthreads();
  for (int i = 0; i < 32; i++) {
    int idx = t + i*512; int r = idx >> 7; int cc = idx & 127;
    dst[idx] = A[r][cc];
  }
}

// ---------------- attention rows -> transposed mix matrices M^T ----------------
__launch_bounds__(128)
__global__ void attn_kernel(float* __restrict__ ws) {
  const int b = blockIdx.x, j = threadIdx.x;
  const bool isimg = (b < 128);
  const int i = isimg ? b : b - 128;
  const float* rowA = ws + (isimg ? OFF_COV_PCD : OFF_COV_IMG) + i*128;
  const float* matA = ws + (isimg ? OFF_INV_IMG : OFF_INV_PCD);
  const float* rowB = ws + (isimg ? OFF_COV_IMG : OFF_COV_PCD) + i*128;
  const float* matB = ws + (isimg ? OFF_COV_IMG : OFF_COV_PCD);
  __shared__ float rA[128], rB[128], red[128];
  rA[j] = rowA[j]; rB[j] = rowB[j];
  __syncthreads();
  float dA = 0.f, dB = 0.f;
#pragma unroll 8
  for (int k = 0; k < 128; k += 4) {
    float4 va = *(const float4*)&matA[j*128 + k];
    float4 vb = *(const float4*)&matB[j*128 + k];
    dA += rA[k]*va.x + rA[k+1]*va.y + rA[k+2]*va.z + rA[k+3]*va.w;
    dB += rB[k]*vb.x + rB[k+1]*vb.y + rB[k+2]*vb.z + rB[k+3]*vb.w;
  }
  dA *= 0.0078125f; dB *= 0.0078125f;
  red[j] = dA; __syncthreads();
  for (int s2 = 64; s2 > 0; s2 >>= 1) { if (j < s2) red[j] = fmaxf(red[j], red[j+s2]); __syncthreads(); }
  float mA = red[0]; __syncthreads();
  float eA = expf(dA - mA);
  red[j] = eA; __syncthreads();
  for (int s2 = 64; s2 > 0; s2 >>= 1) { if (j < s2) red[j] += red[j+s2]; __syncthreads(); }
  float sA = red[0]; __syncthreads();
  red[j] = dB; __syncthreads();
  for (int s2 = 64; s2 > 0; s2 >>= 1) { if (j < s2) red[j] = fmaxf(red[j], red[j+s2]); __syncthreads(); }
  float mB = red[0]; __syncthreads();
  float eB = expf(dB - mB);
  red[j] = eB; __syncthreads();
  for (int s2 = 64; s2 > 0; s2 >>= 1) { if (j < s2) red[j] += red[j+s2]; __syncthreads(); }
  float sB = red[0]; __syncthreads();
  float m = 0.1f * (eA/sA + eB/sB);
  float* MT = ws + (isimg ? OFF_MT_IMG : OFF_MT_PCD);
  MT[j*128 + i] = m;
}

// ---------------- img final: io = M_img @ io + 0.8*img (in place) --------------
__launch_bounds__(512)
__global__ void img_final_kernel(const float* __restrict__ img_in,
                                 const float* __restrict__ ws,
                                 float* __restrict__ io) {
  __shared__ __align__(16) float ts[128][128];
  const int b = blockIdx.x, t = threadIdx.x;
  const int n0 = b * 128;
#pragma unroll
  for (int i = 0; i < 8; i++) {
    int idx = t + i*512; int r = idx >> 5; int c4 = (idx & 31)*4;
    *(float4*)&ts[r][c4] = *(const float4*)&io[(size_t)r*HWSZ + n0 + c4];
  }
  __syncthreads();
  const int c0 = (t >> 5) * 8;
  const int nn0 = (t & 31) * 4;
  const float* Mt = ws + OFF_MT_IMG;
  float acc[8][4];
#pragma unroll
  for (int a = 0; a < 8; a++)
#pragma unroll
    for (int q = 0; q < 4; q++) acc[a][q] = 0.f;
#pragma unroll 4
  for (int k = 0; k < 128; k++) {
    float4 x = *(const float4*)&ts[k][nn0];
    float4 m0 = *(const float4*)&Mt[k*128 + c0];
    float4 m1 = *(const float4*)&Mt[k*128 + c0 + 4];
    float mv[8] = {m0.x,m0.y,m0.z,m0.w,m1.x,m1.y,m1.z,m1.w};
    float xv[4] = {x.x,x.y,x.z,x.w};
#pragma unroll
    for (int a = 0; a < 8; a++)
#pragma unroll
      for (int q = 0; q < 4; q++) acc[a][q] += mv[a]*xv[q];
  }
#pragma unroll
  for (int a = 0; a < 8; a++) {
    size_t off = (size_t)(c0+a)*HWSZ + n0 + nn0;
    float4 orig = *(const float4*)&img_in[off];
    float4 r;
    r.x = acc[a][0] + 0.8f*orig.x;
    r.y = acc[a][1] + 0.8f*orig.y;
    r.z = acc[a][2] + 0.8f*orig.z;
    r.w = acc[a][3] + 0.8f*orig.w;
    *(float4*)&io[off] = r;
  }
}

// ---------------- pcd final: Z = Z @ M_pcd^T + 0.8*pcd (in place) --------------
__launch_bounds__(256)
__global__ void pcd_final_kernel(const float* __restrict__ pcd_in,
                                 const float* __restrict__ ws,
                                 float* __restrict__ Z) {
  __shared__ __align__(16) float Mt[128][132];
  __shared__ __align__(16) float zs[16][132];
  const int b = blockIdx.x, t = threadIdx.x;
  const int n0 = b * 16;
#pragma unroll
  for (int i = 0; i < 16; i++) {
    int idx = t + i*256; int r = idx >> 5; int c4 = (idx & 31)*4;
    *(float4*)&Mt[r][c4] = *(const float4*)&ws[OFF_MT_PCD + r*128 + c4];
  }
#pragma unroll
  for (int i = 0; i < 2; i++) {
    int idx = t + i*256; int r = idx >> 5; int c4 = (idx & 31)*4;
    *(float4*)&zs[r][c4] = *(const float4*)&Z[(size_t)(n0+r)*128 + c4];
  }
  __syncthreads();
  const int nl = t & 15;
  const int c0 = (t >> 4) * 8;
  float acc[8];
#pragma unroll
  for (int q = 0; q < 8; q++) acc[q] = 0.f;
#pragma unroll 8
  for (int k = 0; k < 128; k++) {
    float z = zs[nl][k];
    float4 wa = *(const float4*)&Mt[k][c0];
    float4 wb = *(const float4*)&Mt[k][c0+4];
    acc[0]+=z*wa.x; acc[1]+=z*wa.y; acc[2]+=z*wa.z; acc[3]+=z*wa.w;
    acc[4]+=z*wb.x; acc[5]+=z*wb.y; acc[6]+=z*wb.z; acc[7]+=z*wb.w;
  }
  size_t off = (size_t)(n0+nl)*128 + c0;
  float4 pa = *(const float4*)&pcd_in[off];
  float4 pb = *(const float4*)&pcd_in[off+4];
  float4 r0, r1;
  r0.x = acc[0] + 0.8f*pa.x; r0.y = acc[1] + 0.8f*pa.y;
  r0.z = acc[2] + 0.8f*pa.z; r0.w = acc[3] + 0.8f*pa.w;
  r1.x = acc[4] + 0.8f*pb.x; r1.y = acc[5] + 0.8f*pb.y;
  r1.z = acc[6] + 0.8f*pb.z; r1.w = acc[7] + 0.8f*pb.w;
  *(float4*)&Z[off] = r0; *(float4*)&Z[off+4] = r1;
}

extern "C" void kernel_launch(void* const* d_in, const int* in_sizes, int n_in,
                              void* d_out, int out_size, void* d_ws, size_t ws_size,
                              hipStream_t stream) {
  (void)in_sizes; (void)n_in; (void)out_size;
  const float* img_in = (const float*)d_in[0];
  const float* pcd_in = (const float*)d_in[1];
  const float* conv_w = (const float*)d_in[2];
  const float* conv_b = (const float*)d_in[3];
  const float* gamma  = (const float*)d_in[4];
  const float* beta   = (const float*)d_in[5];
  const float* mean   = (const float*)d_in[6];
  const float* var    = (const float*)d_in[7];
  const float* lin_w  = (const float*)d_in[8];
  const float* lin_b  = (const float*)d_in[9];
  float* out = (float*)d_out;
  float* X = out;            // [128][307200] conv output, transformed in place
  float* Z = out + IMG_SZ;   // [22432][128] linear output, transformed in place
  float* ws = (float*)d_ws;
  const int big = (ws_size >= (size_t)WS_NEED_FLOATS * 4) ? 1 : 0;

  hipLaunchKernelGGL(prep_kernel, dim3(64), dim3(256), 0, stream,
                     conv_w, conv_b, gamma, beta, mean, var, lin_w, ws, big);
  if (big) {
    u16* Timg = (u16*)(ws + OFF_TIMG_F);
    u16* Wb = (u16*)(ws + OFF_WB);
    int nzero = TIMG_U16 / 8;  // uint4 = 8 u16
    hipLaunchKernelGGL(timg_zero_kernel, dim3((nzero + 255)/256), dim3(256), 0, stream,
                       (uint4*)Timg, nzero);
    hipLaunchKernelGGL(timg_kernel, dim3(4800), dim3(256), 0, stream, img_in, Timg);
    hipLaunchKernelGGL(conv_mfma_kernel, dim3(1200), dim3(256), 0, stream, Timg, Wb, ws, X);
  } else {
    hipLaunchKernelGGL(conv_kernel, dim3(4800), dim3(256), 0, stream, img_in, ws, X);
  }
  hipLaunchKernelGGL(linear_kernel, dim3(NPC/16), dim3(256), 0, stream, pcd_in, ws, lin_b, Z);
  hipLaunchKernelGGL(sums_img_kernel, dim3(128), dim3(256), 0, stream, X, ws);
  hipLaunchKernelGGL(sums_pcd_kernel, dim3(128), dim3(256), 0, stream, Z, ws);
  hipLaunchKernelGGL(gram_img_kernel, dim3(NBI), dim3(256), 0, stream, X, ws + OFF_PART_IMG);
  hipLaunchKernelGGL(gram_pcd_kernel, dim3(NBP), dim3(256), 0, stream, Z, ws + OFF_PART_PCD);
  hipLaunchKernelGGL(reduce_cov_kernel, dim3(256), dim3(128), 0, stream, ws);
  hipLaunchKernelGGL(invert_kernel, dim3(2), dim3(512), 0, stream, ws);
  hipLaunchKernelGGL(attn_kernel, dim3(256), dim3(128), 0, stream, ws);
  hipLaunchKernelGGL(img_final_kernel, dim3(HWSZ/128), dim3(512), 0, stream, img_in, ws, X);
  hipLaunchKernelGGL(pcd_final_kernel, dim3(NPC/16), dim3(256), 0, stream, pcd_in, ws, Z);
}

// Round 3
// 914.935 us; speedup vs baseline: 2.3488x; 1.3566x over previous
//
#include <hip/hip_runtime.h>
#include <math.h>

#define HH 480
#define WW 640
#define HWSZ (HH*WW)        // 307200
#define NPC 22432
#define IMG_SZ (128*HWSZ)   // 39321600
#define NBI 256             // gram img partial blocks
#define NBP 64              // gram pcd partial blocks
#define CHUNK_I 1200        // 256*1200 = 307200
#define CHUNK_P 351         // 64*351 = 22464 >= 22432

typedef unsigned short u16;
typedef unsigned int u32;
typedef __attribute__((ext_vector_type(8))) short bf16x8;
typedef __attribute__((ext_vector_type(4))) float f32x4;

// ws float offsets
#define OFF_SUMS_IMG 0
#define OFF_SUMS_PCD 128
#define OFF_BIAS2    256
#define OFF_COV_IMG  512
#define OFF_COV_PCD  16896
#define OFF_INV_IMG  33280
#define OFF_INV_PCD  49664
#define OFF_MT_IMG   66048
#define OFF_MT_PCD   82432
#define OFF_LWT      98816
#define OFF_PSUMS    115200      // 256*128 = 32768
#define OFF_MB       147968     // M_img bf16 [c][k]: 16384 u16 = 4096 floats
#define OFF_WT       152064     // 128*9*128 fp32 (fallback conv) = 147456
#define OFF_PART_IMG 299520     // NBI*16384 = 4194304
#define OFF_PART_PCD 4493824    // NBP*16384 = 1048576
#define OFF_WB       5542400    // 9*128*128 bf16 = 73728 floats
#define OFF_TIMG_F   5616128    // 482*642*128 bf16 = 19804416 floats
#define TIMG_PAD_W 642
#define TIMG_PX (482*642)       // 309444
#define TIMG_U16 (TIMG_PX*128)  // 39608832
#define WS_NEED_FLOATS 25420544

__device__ inline u32 pack_bf16(float a, float b) {
  u32 ua = __float_as_uint(a), ub = __float_as_uint(b);
  ua += 0x7FFFu + ((ua >> 16) & 1u);
  ub += 0x7FFFu + ((ub >> 16) & 1u);
  return (ua >> 16) | (ub & 0xFFFF0000u);
}

// ---------------- prep: fold BN into conv weights, transpose linear weights ----
__global__ void prep_kernel(const float* __restrict__ conv_w, const float* __restrict__ conv_b,
                            const float* __restrict__ gamma, const float* __restrict__ beta,
                            const float* __restrict__ mean, const float* __restrict__ var,
                            const float* __restrict__ lin_w, float* __restrict__ ws, int big) {
  int tid = blockIdx.x * blockDim.x + threadIdx.x;
  int nth = gridDim.x * blockDim.x;
  for (int oc = tid; oc < 128; oc += nth) {
    float s = gamma[oc] / sqrtf(var[oc] + 1e-5f);
    ws[OFF_BIAS2 + oc] = (conv_b[oc] - mean[oc]) * s + beta[oc];
  }
  if (big) {
    // Wb bf16 [tap][oc][ci]
    u16* Wb = (u16*)(ws + OFF_WB);
    for (int e = tid; e < 9*128*128; e += nth) {
      int ci = e & 127; int oc = (e >> 7) & 127; int tap = e >> 14;
      float s = gamma[oc] / sqrtf(var[oc] + 1e-5f);
      float v = conv_w[(oc*128 + ci)*9 + tap] * s;
      u32 u = __float_as_uint(v); u += 0x7FFFu + ((u >> 16) & 1u);
      Wb[e] = (u16)(u >> 16);
    }
  } else {
    // fp32 wT[ci][k][oc] = conv_w[oc][ci][k] * s[oc]
    for (int e = tid; e < 128*9*128; e += nth) {
      int oc = e & 127; int k = (e >> 7) % 9; int ci = e / 1152;
      float s = gamma[oc] / sqrtf(var[oc] + 1e-5f);
      ws[OFF_WT + e] = conv_w[(oc*128 + ci)*9 + k] * s;
    }
  }
  // lwT[k][c] = lin_w[c][k]
  for (int e = tid; e < 128*128; e += nth) {
    int c2 = e & 127; int k = e >> 7;
    ws[OFF_LWT + e] = lin_w[c2*128 + k];
  }
}

// ---------------- zero only Timg border (rest is fully overwritten) ------------
__global__ void timg_border_kernel(uint4* __restrict__ p) {
  int tid = blockIdx.x * blockDim.x + threadIdx.x;
  const int NB = (642*2 + 480*2);           // 2244 border pixels
  if (tid >= NB * 16) return;
  int px = tid >> 4, q = tid & 15;
  int addr;
  if (px < 642) addr = px;                                // row 0
  else if (px < 1284) addr = 481*642 + (px - 642);        // row 481
  else if (px < 1764) addr = (px - 1284 + 1) * 642;       // col 0, rows 1..480
  else addr = (px - 1764 + 1) * 642 + 641;                // col 641
  p[(size_t)addr * 16 + q] = make_uint4(0u, 0u, 0u, 0u);
}

// ---------------- img fp32 [128][480][640] -> Timg bf16 padded [482*642][128] --
__launch_bounds__(256)
__global__ void timg_kernel(const float* __restrict__ img, u16* __restrict__ Timg) {
  __shared__ float xt[64][133];
  const int b = blockIdx.x;
  const int h = b / 10, w0 = (b % 10) * 64;
  const int t = threadIdx.x;
  const int wl = t & 63, cib = t >> 6;
#pragma unroll
  for (int i = 0; i < 32; ++i) {
    int ci = cib + i*4;
    xt[wl][ci] = img[(size_t)ci*HWSZ + h*WW + w0 + wl];
  }
  __syncthreads();
  const int wp = t >> 2, c0 = (t & 3) * 32;
  u32 out[16];
#pragma unroll
  for (int j = 0; j < 16; ++j) {
    float a = xt[wp][c0 + 2*j], bb = xt[wp][c0 + 2*j + 1];
    out[j] = pack_bf16(a, bb);
  }
  u16* dst = Timg + ((size_t)(h+1)*TIMG_PAD_W + (w0 + 1 + wp)) * 128 + c0;
#pragma unroll
  for (int q = 0; q < 4; ++q)
    *(uint4*)(dst + q*8) = make_uint4(out[q*4], out[q*4+1], out[q*4+2], out[q*4+3]);
}

// ---------------- conv via 9-tap implicit GEMM, bf16 MFMA ----------------------
__launch_bounds__(256)
__global__ void conv_mfma_kernel(const u16* __restrict__ Timg,
                                 const u16* __restrict__ Wb,
                                 const float* __restrict__ ws,
                                 float* __restrict__ X) {
  const int b = blockIdx.x;
  const int h0 = (b / 10) * 4;
  const int w0 = (b % 10) * 64;
  const int t = threadIdx.x;
  const int wv = t >> 6;
  const int l = t & 63;
  const int n_lane = l & 15;
  const int k_lane = l >> 4;
  const int px_center = (h0 + wv + 1) * TIMG_PAD_W + (w0 + 1) + n_lane;

  f32x4 acc[8][4];
#pragma unroll
  for (int mt = 0; mt < 8; ++mt)
#pragma unroll
    for (int nt = 0; nt < 4; ++nt) acc[mt][nt] = (f32x4){0.f,0.f,0.f,0.f};

  const int toff[9] = {-TIMG_PAD_W-1, -TIMG_PAD_W, -TIMG_PAD_W+1,
                       -1, 0, 1,
                       TIMG_PAD_W-1, TIMG_PAD_W, TIMG_PAD_W+1};
  const u16* ab0 = Wb + n_lane*128 + k_lane*8;
#pragma unroll 1
  for (int tap = 0; tap < 9; ++tap) {
    const u16* bb = Timg + (size_t)(px_center + toff[tap]) * 128 + k_lane*8;
    const u16* ab = ab0 + tap*16384;
#pragma unroll
    for (int ci0 = 0; ci0 < 128; ci0 += 32) {
      bf16x8 Bf[4], Af[8];
#pragma unroll
      for (int nt = 0; nt < 4; ++nt) Bf[nt] = *(const bf16x8*)(bb + nt*2048 + ci0);
#pragma unroll
      for (int mt = 0; mt < 8; ++mt) Af[mt] = *(const bf16x8*)(ab + mt*2048 + ci0);
#pragma unroll
      for (int mt = 0; mt < 8; ++mt)
#pragma unroll
        for (int nt = 0; nt < 4; ++nt)
          acc[mt][nt] = __builtin_amdgcn_mfma_f32_16x16x32_bf16(Af[mt], Bf[nt], acc[mt][nt], 0, 0, 0);
    }
  }
  const float* bias = ws + OFF_BIAS2;
  const int pxw = (h0 + wv) * WW + w0 + n_lane;
#pragma unroll
  for (int mt = 0; mt < 8; ++mt) {
    f32x4 bv = *(const f32x4*)(bias + mt*16 + k_lane*4);
#pragma unroll
    for (int nt = 0; nt < 4; ++nt) {
#pragma unroll
      for (int r = 0; r < 4; ++r) {
        int oc = mt*16 + k_lane*4 + r;
        float v = acc[mt][nt][r] + bv[r];
        X[(size_t)oc*HWSZ + pxw + nt*16] = fmaxf(v, 0.f);
      }
    }
  }
}

// ---------------- fp32 fallback conv -------------------------------------------
__launch_bounds__(256)
__global__ void conv_kernel(const float* __restrict__ img,
                            const float* __restrict__ ws,
                            float* __restrict__ outX) {
  __shared__ __align__(16) float xs[8][10][20];
  __shared__ __align__(16) float wsm[8][9][64];
  const int b = blockIdx.x;
  const int oc0 = (b & 1) * 64;
  const int sidx = b >> 1;
  const int h0 = (sidx / 40) * 8;
  const int w0 = (sidx % 40) * 16;
  const int t = threadIdx.x;
  const int oc_t = t & 15;
  const int px_t = t >> 4;
  const int ph = px_t >> 1;
  const int pw0 = (px_t & 1) * 8;
  float acc[4][8];
#pragma unroll
  for (int o = 0; o < 4; o++)
#pragma unroll
    for (int m = 0; m < 8; m++) acc[o][m] = 0.f;
  const float* wT = ws + OFF_WT;
  for (int ci0 = 0; ci0 < 128; ci0 += 8) {
    __syncthreads();
    for (int e = t; e < 1440; e += 256) {
      int ci = e / 180; int rem = e - ci*180; int r = rem / 18; int cc2 = rem - r*18;
      int gh = h0 + r - 1, gw = w0 + cc2 - 1;
      float v = 0.f;
      if ((unsigned)gh < (unsigned)HH && (unsigned)gw < (unsigned)WW)
        v = img[(ci0+ci)*HWSZ + gh*WW + gw];
      xs[ci][r][cc2] = v;
    }
    for (int e = t; e < 4608; e += 256) {
      int oc = e & 63; int k = (e >> 6) % 9; int ci = e / 576;
      wsm[ci][k][oc] = wT[((ci0+ci)*9 + k)*128 + oc0 + oc];
    }
    __syncthreads();
#pragma unroll
    for (int ci = 0; ci < 8; ci++) {
#pragma unroll
      for (int kh = 0; kh < 3; kh++) {
        float x10[10];
        float4 xa = *(const float4*)&xs[ci][ph+kh][pw0];
        float4 xb = *(const float4*)&xs[ci][ph+kh][pw0+4];
        x10[0]=xa.x; x10[1]=xa.y; x10[2]=xa.z; x10[3]=xa.w;
        x10[4]=xb.x; x10[5]=xb.y; x10[6]=xb.z; x10[7]=xb.w;
        x10[8]=xs[ci][ph+kh][pw0+8]; x10[9]=xs[ci][ph+kh][pw0+9];
#pragma unroll
        for (int kw = 0; kw < 3; kw++) {
          float4 wv = *(const float4*)&wsm[ci][kh*3+kw][oc_t*4];
#pragma unroll
          for (int m = 0; m < 8; m++) {
            float xv = x10[kw+m];
            acc[0][m] += wv.x*xv; acc[1][m] += wv.y*xv;
            acc[2][m] += wv.z*xv; acc[3][m] += wv.w*xv;
          }
        }
      }
    }
  }
#pragma unroll
  for (int o = 0; o < 4; o++) {
    int oc = oc0 + oc_t*4 + o;
    float bias = ws[OFF_BIAS2 + oc];
    float4 r0, r1;
    r0.x = fmaxf(acc[o][0]+bias, 0.f); r0.y = fmaxf(acc[o][1]+bias, 0.f);
    r0.z = fmaxf(acc[o][2]+bias, 0.f); r0.w = fmaxf(acc[o][3]+bias, 0.f);
    r1.x = fmaxf(acc[o][4]+bias, 0.f); r1.y = fmaxf(acc[o][5]+bias, 0.f);
    r1.z = fmaxf(acc[o][6]+bias, 0.f); r1.w = fmaxf(acc[o][7]+bias, 0.f);
    float* dst = outX + (size_t)oc*HWSZ + (h0+ph)*WW + w0 + pw0;
    *(float4*)dst = r0; *(float4*)(dst+4) = r1;
  }
}

// ---------------- linear + ReLU -> Z -------------------------------------------
__launch_bounds__(256)
__global__ void linear_kernel(const float* __restrict__ pcd,
                              const float* __restrict__ ws,
                              const float* __restrict__ lin_b,
                              float* __restrict__ Z) {
  __shared__ __align__(16) float Mt[128][132];
  __shared__ __align__(16) float zs[16][132];
  const int b = blockIdx.x, t = threadIdx.x;
  const int n0 = b * 16;
#pragma unroll
  for (int i = 0; i < 16; i++) {
    int idx = t + i*256; int r = idx >> 5; int c4 = (idx & 31)*4;
    *(float4*)&Mt[r][c4] = *(const float4*)&ws[OFF_LWT + r*128 + c4];
  }
#pragma unroll
  for (int i = 0; i < 2; i++) {
    int idx = t + i*256; int r = idx >> 5; int c4 = (idx & 31)*4;
    *(float4*)&zs[r][c4] = *(const float4*)&pcd[(size_t)(n0+r)*128 + c4];
  }
  __syncthreads();
  const int nl = t & 15;
  const int c0 = (t >> 4) * 8;
  float acc[8];
#pragma unroll
  for (int q = 0; q < 8; q++) acc[q] = 0.f;
#pragma unroll 8
  for (int k = 0; k < 128; k++) {
    float z = zs[nl][k];
    float4 wa = *(const float4*)&Mt[k][c0];
    float4 wb = *(const float4*)&Mt[k][c0+4];
    acc[0]+=z*wa.x; acc[1]+=z*wa.y; acc[2]+=z*wa.z; acc[3]+=z*wa.w;
    acc[4]+=z*wb.x; acc[5]+=z*wb.y; acc[6]+=z*wb.z; acc[7]+=z*wb.w;
  }
  float4 ba = *(const float4*)&lin_b[c0];
  float4 bb = *(const float4*)&lin_b[c0+4];
  float4 r0, r1;
  r0.x = fmaxf(acc[0]+ba.x,0.f); r0.y = fmaxf(acc[1]+ba.y,0.f);
  r0.z = fmaxf(acc[2]+ba.z,0.f); r0.w = fmaxf(acc[3]+ba.w,0.f);
  r1.x = fmaxf(acc[4]+bb.x,0.f); r1.y = fmaxf(acc[5]+bb.y,0.f);
  r1.z = fmaxf(acc[6]+bb.z,0.f); r1.w = fmaxf(acc[7]+bb.w,0.f);
  float* dst = Z + (size_t)(n0+nl)*128 + c0;
  *(float4*)dst = r0; *(float4*)(dst+4) = r1;
}

// ---------------- pcd channel sums ---------------------------------------------
__launch_bounds__(256)
__global__ void sums_pcd_kernel(const float* __restrict__ Z, float* __restrict__ ws) {
  const int c = blockIdx.x, t = threadIdx.x;
  float s = 0.f;
  for (int n = t; n < NPC; n += 256) s += Z[(size_t)n*128 + c];
  __shared__ float red[256];
  red[t] = s; __syncthreads();
  for (int s2 = 128; s2 > 0; s2 >>= 1) { if (t < s2) red[t] += red[t+s2]; __syncthreads(); }
  if (t == 0) ws[OFF_SUMS_PCD + c] = red[0];
}

// ---------------- gram img via MFMA (bf16 LDS tile, fused channel sums) --------
// block b: full 128x128 gram partial over px chunk [b*1200, (b+1)*1200)
__launch_bounds__(256)
__global__ void gram_img_mfma_kernel(const float* __restrict__ X,
                                     float* __restrict__ part,
                                     float* __restrict__ psums) {
  __shared__ __align__(16) u16 tile[128*64];   // [c][px64] bf16, XOR-swizzled
  const int b = blockIdx.x, t = threadIdx.x;
  const int px0 = b * CHUNK_I;
  const int pg = t & 15;            // staging: px granule (4 px)
  const int g0 = t >> 4;            // staging: channel group base (16 c per pass)
  const int wv = t >> 6, l = t & 63;
  const int i0 = (wv >> 1) * 64, j0 = (wv & 1) * 64;
  const int row16 = l & 15, kq = l >> 4;
  float csum[8];
#pragma unroll
  for (int q = 0; q < 8; ++q) csum[q] = 0.f;
  f32x4 acc[4][4];
#pragma unroll
  for (int a = 0; a < 4; ++a)
#pragma unroll
    for (int q = 0; q < 4; ++q) acc[a][q] = (f32x4){0.f,0.f,0.f,0.f};

  for (int ti = 0; ti < 19; ++ti) {
    const int plg = ti*64 + pg*4;   // local px of this granule
    float4 v[8];
    if (ti < 18) {
#pragma unroll
      for (int cc = 0; cc < 8; ++cc) {
        int c = g0 + cc*16;
        v[cc] = *(const float4*)(X + (size_t)c*HWSZ + px0 + plg);
      }
    } else {
#pragma unroll
      for (int cc = 0; cc < 8; ++cc) {
        int c = g0 + cc*16;
        const float* src = X + (size_t)c*HWSZ + px0;
#pragma unroll
        for (int j = 0; j < 4; ++j) {
          int p = plg + j;
          ((float*)&v[cc])[j] = (p < CHUNK_I) ? src[p] : 0.f;
        }
      }
    }
    __syncthreads();   // previous tile fully consumed
#pragma unroll
    for (int cc = 0; cc < 8; ++cc) {
      int c = g0 + cc*16;
      csum[cc] += v[cc].x + v[cc].y + v[cc].z + v[cc].w;
      u32 w0 = pack_bf16(v[cc].x, v[cc].y);
      u32 w1 = pack_bf16(v[cc].z, v[cc].w);
      *(uint2*)((char*)tile + c*128 + ((pg*8) ^ ((c & 7) << 4))) = make_uint2(w0, w1);
    }
    __syncthreads();
#pragma unroll
    for (int f = 0; f < 2; ++f) {
      bf16x8 Af[4], Bf[4];
#pragma unroll
      for (int mt = 0; mt < 4; ++mt) {
        int c = i0 + mt*16 + row16;
        Af[mt] = *(const bf16x8*)((char*)tile + c*128 + ((f*64 + kq*16) ^ ((c & 7) << 4)));
      }
#pragma unroll
      for (int nt = 0; nt < 4; ++nt) {
        int c = j0 + nt*16 + row16;
        Bf[nt] = *(const bf16x8*)((char*)tile + c*128 + ((f*64 + kq*16) ^ ((c & 7) << 4)));
      }
#pragma unroll
      for (int mt = 0; mt < 4; ++mt)
#pragma unroll
        for (int nt = 0; nt < 4; ++nt)
          acc[mt][nt] = __builtin_amdgcn_mfma_f32_16x16x32_bf16(Af[mt], Bf[nt], acc[mt][nt], 0, 0, 0);
    }
  }
  // channel partial sums: reduce across the 16 px-granule lanes (same wave)
#pragma unroll
  for (int cc = 0; cc < 8; ++cc) {
    float s = csum[cc];
    s += __shfl_xor(s, 1, 64);
    s += __shfl_xor(s, 2, 64);
    s += __shfl_xor(s, 4, 64);
    s += __shfl_xor(s, 8, 64);
    if (pg == 0) psums[b*128 + g0 + cc*16] = s;
  }
  // store partial gram (deterministic per-block buffer)
  float* dst = part + (size_t)b*16384;
#pragma unroll
  for (int mt = 0; mt < 4; ++mt)
#pragma unroll
    for (int nt = 0; nt < 4; ++nt) {
#pragma unroll
      for (int r = 0; r < 4; ++r) {
        int i = i0 + mt*16 + kq*4 + r;
        int j = j0 + nt*16 + row16;
        dst[i*128 + j] = acc[mt][nt][r];
      }
    }
}

// ---------------- reduce img psums -> SUMS_IMG ---------------------------------
__global__ void psums_reduce_kernel(float* __restrict__ ws) {
  int t = threadIdx.x;  // 128
  float s = 0.f;
  const float* ps = ws + OFF_PSUMS;
  for (int b = 0; b < NBI; ++b) s += ps[b*128 + t];
  ws[OFF_SUMS_IMG + t] = s;
}

// ---------------- gram pcd (fp32, unchanged) -----------------------------------
__launch_bounds__(256)
__global__ void gram_pcd_kernel(const float* __restrict__ Z, float* __restrict__ part) {
  __shared__ __align__(16) float zt[64][132];
  const int b = blockIdx.x, t = threadIdx.x;
  const int n0 = b * CHUNK_P;
  const int i0 = (t >> 4) * 8, j0 = (t & 15) * 8;
  float acc[8][8];
#pragma unroll
  for (int a = 0; a < 8; a++)
#pragma unroll
    for (int q = 0; q < 8; q++) acc[a][q] = 0.f;
  for (int tile = 0; tile < 6; tile++) {
    __syncthreads();
#pragma unroll
    for (int i = 0; i < 8; i++) {
      int idx = t + i*256; int r = idx >> 5; int c4 = (idx & 31)*4;
      int lrow = tile*64 + r;
      int n = n0 + lrow;
      float4 v = {0.f,0.f,0.f,0.f};
      if (lrow < CHUNK_P && n < NPC) v = *(const float4*)&Z[(size_t)n*128 + c4];
      *(float4*)&zt[r][c4] = v;
    }
    __syncthreads();
#pragma unroll 4
    for (int n = 0; n < 64; n++) {
      float4 a0 = *(const float4*)&zt[n][i0];
      float4 a1 = *(const float4*)&zt[n][i0+4];
      float4 b0 = *(const float4*)&zt[n][j0];
      float4 b1 = *(const float4*)&zt[n][j0+4];
      float av[8] = {a0.x,a0.y,a0.z,a0.w,a1.x,a1.y,a1.z,a1.w};
      float bv[8] = {b0.x,b0.y,b0.z,b0.w,b1.x,b1.y,b1.z,b1.w};
#pragma unroll
      for (int a = 0; a < 8; a++)
#pragma unroll
        for (int q = 0; q < 8; q++) acc[a][q] += av[a]*bv[q];
    }
  }
  float* dst = part + (size_t)b*16384;
#pragma unroll
  for (int a = 0; a < 8; a++) {
    float4 w0v = {acc[a][0],acc[a][1],acc[a][2],acc[a][3]};
    float4 w1v = {acc[a][4],acc[a][5],acc[a][6],acc[a][7]};
    *(float4*)&dst[(i0+a)*128 + j0] = w0v;
    *(float4*)&dst[(i0+a)*128 + j0 + 4] = w1v;
  }
}

// ---------------- reduce partials -> cov ---------------------------------------
__launch_bounds__(128)
__global__ void reduce_cov_kernel(float* __restrict__ ws) {
  const int b = blockIdx.x, t = threadIdx.x;
  const bool isimg = (b < 128);
  const int i = isimg ? b : b - 128;
  const int nparts = isimg ? NBI : NBP;
  const float* part = ws + (isimg ? OFF_PART_IMG : OFF_PART_PCD);
  float g = 0.f;
  for (int p = 0; p < nparts; p++) g += part[(size_t)p*16384 + i*128 + t];
  float Si = ws[(isimg ? OFF_SUMS_IMG : OFF_SUMS_PCD) + i];
  float Sj = ws[(isimg ? OFF_SUMS_IMG : OFF_SUMS_PCD) + t];
  float n = isimg ? (float)HWSZ : (float)NPC;
  float cov = (g - Si*Sj/n) / (n - 1.f);
  ws[(isimg ? OFF_COV_IMG : OFF_COV_PCD) + i*128 + t] = cov;
}

// ---------------- in-place Gauss-Jordan inverse of (cov + 1e-6 I) --------------
__launch_bounds__(512)
__global__ void invert_kernel(float* __restrict__ ws) {
  __shared__ __align__(16) float A[128][132];
  const int b = blockIdx.x, t = threadIdx.x;
  const float* src = ws + (b == 0 ? OFF_COV_IMG : OFF_COV_PCD);
  float* dst = ws + (b == 0 ? OFF_INV_IMG : OFF_INV_PCD);
  for (int i = 0; i < 32; i++) {
    int idx = t + i*512; int r = idx >> 7; int cc = idx & 127;
    A[r][cc] = src[idx] + (r == cc ? 1e-6f : 0.f);
  }
  const int row = t >> 2;
  const int cbase = (t & 3) * 32;
  for (int k = 0; k < 128; k++) {
    __syncthreads();
    float ip = 1.f / A[k][k];
    float f = (row != k) ? A[row][k] : 0.f;
    __syncthreads();
    if (t < 128) A[k][t] = (t == k) ? ip : A[k][t] * ip;
    __syncthreads();
    if (row != k) {
#pragma unroll
      for (int cc = 0; cc < 8; cc++) {
        int c4 = cbase + cc*4;
        float4 v = *(const float4*)&A[row][c4];
        float4 p = *(const float4*)&A[k][c4];
        v.x -= f*p.x; v.y -= f*p.y; v.z -= f*p.z; v.w -= f*p.w;
        if (k >= c4 && k < c4+4) {
          float nv = -f*ip;
          if (k == c4) v.x = nv; else if (k == c4+1) v.y = nv;
          else if (k == c4+2) v.z = nv; else v.w = nv;
        }
        *(float4*)&A[row][c4] = v;
      }
    }
  }
  __syncthreads();
  for (int i = 0; i < 32; i++) {
    int idx = t + i*512; int r = idx >> 7; int cc = idx & 127;
    dst[idx] = A[r][cc];
  }
}

// ---------------- attention rows -> transposed mix matrices M^T ----------------
__launch_bounds__(128)
__global__ void attn_kernel(float* __restrict__ ws) {
  const int b = blockIdx.x, j = threadIdx.x;
  const bool isimg = (b < 128);
  const int i = isimg ? b : b - 128;
  const float* rowA = ws + (isimg ? OFF_COV_PCD : OFF_COV_IMG) + i*128;
  const float* matA = ws + (isimg ? OFF_INV_IMG : OFF_INV_PCD);
  const float* rowB = ws + (isimg ? OFF_COV_IMG : OFF_COV_PCD) + i*128;
  const float* matB = ws + (isimg ? OFF_COV_IMG : OFF_COV_PCD);
  __shared__ float rA[128], rB[128], red[128];
  rA[j] = rowA[j]; rB[j] = rowB[j];
  __syncthreads();
  float dA = 0.f, dB = 0.f;
#pragma unroll 8
  for (int k = 0; k < 128; k += 4) {
    float4 va = *(const float4*)&matA[j*128 + k];
    float4 vb = *(const float4*)&matB[j*128 + k];
    dA += rA[k]*va.x + rA[k+1]*va.y + rA[k+2]*va.z + rA[k+3]*va.w;
    dB += rB[k]*vb.x + rB[k+1]*vb.y + rB[k+2]*vb.z + rB[k+3]*vb.w;
  }
  dA *= 0.0078125f; dB *= 0.0078125f;
  red[j] = dA; __syncthreads();
  for (int s2 = 64; s2 > 0; s2 >>= 1) { if (j < s2) red[j] = fmaxf(red[j], red[j+s2]); __syncthreads(); }
  float mA = red[0]; __syncthreads();
  float eA = expf(dA - mA);
  red[j] = eA; __syncthreads();
  for (int s2 = 64; s2 > 0; s2 >>= 1) { if (j < s2) red[j] += red[j+s2]; __syncthreads(); }
  float sA = red[0]; __syncthreads();
  red[j] = dB; __syncthreads();
  for (int s2 = 64; s2 > 0; s2 >>= 1) { if (j < s2) red[j] = fmaxf(red[j], red[j+s2]); __syncthreads(); }
  float mB = red[0]; __syncthreads();
  float eB = expf(dB - mB);
  red[j] = eB; __syncthreads();
  for (int s2 = 64; s2 > 0; s2 >>= 1) { if (j < s2) red[j] += red[j+s2]; __syncthreads(); }
  float sB = red[0]; __syncthreads();
  float m = 0.1f * (eA/sA + eB/sB);
  float* MT = ws + (isimg ? OFF_MT_IMG : OFF_MT_PCD);
  MT[j*128 + i] = m;
}

// ---------------- M_img fp32 [k][c] -> Mb bf16 [c][k] --------------------------
__global__ void mb_kernel(float* __restrict__ ws) {
  int e = blockIdx.x * 256 + threadIdx.x;   // 8192 threads
  int c = e >> 6, kp = e & 63;
  float lo = ws[OFF_MT_IMG + (2*kp)*128 + c];
  float hi = ws[OFF_MT_IMG + (2*kp+1)*128 + c];
  ((u32*)(ws + OFF_MB))[c*64 + kp] = pack_bf16(lo, hi);
}

// ---------------- img final via MFMA: io = M@io + 0.8*img (in place) -----------
__launch_bounds__(256)
__global__ void img_final_mfma_kernel(const float* __restrict__ img_in,
                                      const float* __restrict__ ws,
                                      float* __restrict__ io) {
  __shared__ __align__(16) u16 bt[128*128];   // [px][c] bf16, XOR-swizzled, 32KB
  const int blk = blockIdx.x, t = threadIdx.x;
  const int px0 = blk * 128;
  // staging: transpose X[c][px-tile] fp32 -> bt[px][c] bf16
  const int pxg = (t & 31) * 4;     // px granule
  const int cp0 = t >> 5;           // channel-pair base (0..7)
#pragma unroll
  for (int cc = 0; cc < 8; ++cc) {
    int cpair = cp0 + cc*8;
    const float* s0 = io + (size_t)(2*cpair)*HWSZ + px0 + pxg;
    float4 a = *(const float4*)s0;
    float4 b4 = *(const float4*)(s0 + HWSZ);
#pragma unroll
    for (int j = 0; j < 4; ++j) {
      int pxl = pxg + j;
      *(u32*)((char*)bt + pxl*256 + ((cpair*4) ^ ((pxl & 7) << 4))) =
          pack_bf16(((const float*)&a)[j], ((const float*)&b4)[j]);
    }
  }
  __syncthreads();
  const int wv = t >> 6, l = t & 63;
  const int i0 = (wv >> 1) * 64, j0 = (wv & 1) * 64;
  const int row16 = l & 15, kq = l >> 4;
  const u16* Mb = (const u16*)(ws + OFF_MB);
  f32x4 acc[4][4];
#pragma unroll
  for (int a = 0; a < 4; ++a)
#pragma unroll
    for (int q = 0; q < 4; ++q) acc[a][q] = (f32x4){0.f,0.f,0.f,0.f};
#pragma unroll
  for (int f = 0; f < 4; ++f) {
    bf16x8 Bf[4], Am[4];
#pragma unroll
    for (int nt = 0; nt < 4; ++nt) {
      int pxl = j0 + nt*16 + row16;
      Bf[nt] = *(const bf16x8*)((char*)bt + pxl*256 + ((f*64 + kq*16) ^ ((pxl & 7) << 4)));
    }
#pragma unroll
    for (int mt = 0; mt < 4; ++mt) {
      int c = i0 + mt*16 + row16;
      Am[mt] = *(const bf16x8*)((const char*)Mb + c*256 + f*64 + kq*16);
    }
#pragma unroll
    for (int mt = 0; mt < 4; ++mt)
#pragma unroll
      for (int nt = 0; nt < 4; ++nt)
        acc[mt][nt] = __builtin_amdgcn_mfma_f32_16x16x32_bf16(Am[mt], Bf[nt], acc[mt][nt], 0, 0, 0);
  }
  // epilogue: out = acc + 0.8*img  (this block's px range was fully staged)
#pragma unroll
  for (int mt = 0; mt < 4; ++mt)
#pragma unroll
    for (int nt = 0; nt < 4; ++nt) {
      int pxl = j0 + nt*16 + row16;
#pragma unroll
      for (int r = 0; r < 4; ++r) {
        int c = i0 + mt*16 + kq*4 + r;
        size_t off = (size_t)c*HWSZ + px0 + pxl;
        io[off] = acc[mt][nt][r] + 0.8f*img_in[off];
      }
    }
}

// ---------------- pcd final: Z = Z @ M_pcd^T + 0.8*pcd (in place) --------------
__launch_bounds__(256)
__global__ void pcd_final_kernel(const float* __restrict__ pcd_in,
                                 const float* __restrict__ ws,
                                 float* __restrict__ Z) {
  __shared__ __align__(16) float Mt[128][132];
  __shared__ __align__(16) float zs[16][132];
  const int b = blockIdx.x, t = threadIdx.x;
  const int n0 = b * 16;
#pragma unroll
  for (int i = 0; i < 16; i++) {
    int idx = t + i*256; int r = idx >> 5; int c4 = (idx & 31)*4;
    *(float4*)&Mt[r][c4] = *(const float4*)&ws[OFF_MT_PCD + r*128 + c4];
  }
#pragma unroll
  for (int i = 0; i < 2; i++) {
    int idx = t + i*256; int r = idx >> 5; int c4 = (idx & 31)*4;
    *(float4*)&zs[r][c4] = *(const float4*)&Z[(size_t)(n0+r)*128 + c4];
  }
  __syncthreads();
  const int nl = t & 15;
  const int c0 = (t >> 4) * 8;
  float acc[8];
#pragma unroll
  for (int q = 0; q < 8; q++) acc[q] = 0.f;
#pragma unroll 8
  for (int k = 0; k < 128; k++) {
    float z = zs[nl][k];
    float4 wa = *(const float4*)&Mt[k][c0];
    float4 wb = *(const float4*)&Mt[k][c0+4];
    acc[0]+=z*wa.x; acc[1]+=z*wa.y; acc[2]+=z*wa.z; acc[3]+=z*wa.w;
    acc[4]+=z*wb.x; acc[5]+=z*wb.y; acc[6]+=z*wb.z; acc[7]+=z*wb.w;
  }
  size_t off = (size_t)(n0+nl)*128 + c0;
  float4 pa = *(const float4*)&pcd_in[off];
  float4 pb = *(const float4*)&pcd_in[off+4];
  float4 r0, r1;
  r0.x = acc[0] + 0.8f*pa.x; r0.y = acc[1] + 0.8f*pa.y;
  r0.z = acc[2] + 0.8f*pa.z; r0.w = acc[3] + 0.8f*pa.w;
  r1.x = acc[4] + 0.8f*pb.x; r1.y = acc[5] + 0.8f*pb.y;
  r1.z = acc[6] + 0.8f*pb.z; r1.w = acc[7] + 0.8f*pb.w;
  *(float4*)&Z[off] = r0; *(float4*)&Z[off+4] = r1;
}

extern "C" void kernel_launch(void* const* d_in, const int* in_sizes, int n_in,
                              void* d_out, int out_size, void* d_ws, size_t ws_size,
                              hipStream_t stream) {
  (void)in_sizes; (void)n_in; (void)out_size;
  const float* img_in = (const float*)d_in[0];
  const float* pcd_in = (const float*)d_in[1];
  const float* conv_w = (const float*)d_in[2];
  const float* conv_b = (const float*)d_in[3];
  const float* gamma  = (const float*)d_in[4];
  const float* beta   = (const float*)d_in[5];
  const float* mean   = (const float*)d_in[6];
  const float* var    = (const float*)d_in[7];
  const float* lin_w  = (const float*)d_in[8];
  const float* lin_b  = (const float*)d_in[9];
  float* out = (float*)d_out;
  float* X = out;            // [128][307200] conv output, transformed in place
  float* Z = out + IMG_SZ;   // [22432][128] linear output, transformed in place
  float* ws = (float*)d_ws;
  const int big = (ws_size >= (size_t)WS_NEED_FLOATS * 4) ? 1 : 0;

  hipLaunchKernelGGL(prep_kernel, dim3(64), dim3(256), 0, stream,
                     conv_w, conv_b, gamma, beta, mean, var, lin_w, ws, big);
  if (big) {
    u16* Timg = (u16*)(ws + OFF_TIMG_F);
    u16* Wb = (u16*)(ws + OFF_WB);
    hipLaunchKernelGGL(timg_border_kernel, dim3(141), dim3(256), 0, stream, (uint4*)Timg);
    hipLaunchKernelGGL(timg_kernel, dim3(4800), dim3(256), 0, stream, img_in, Timg);
    hipLaunchKernelGGL(conv_mfma_kernel, dim3(1200), dim3(256), 0, stream, Timg, Wb, ws, X);
  } else {
    hipLaunchKernelGGL(conv_kernel, dim3(4800), dim3(256), 0, stream, img_in, ws, X);
  }
  hipLaunchKernelGGL(linear_kernel, dim3(NPC/16), dim3(256), 0, stream, pcd_in, ws, lin_b, Z);
  hipLaunchKernelGGL(gram_img_mfma_kernel, dim3(NBI), dim3(256), 0, stream,
                     X, ws + OFF_PART_IMG, ws + OFF_PSUMS);
  hipLaunchKernelGGL(psums_reduce_kernel, dim3(1), dim3(128), 0, stream, ws);
  hipLaunchKernelGGL(sums_pcd_kernel, dim3(128), dim3(256), 0, stream, Z, ws);
  hipLaunchKernelGGL(gram_pcd_kernel, dim3(NBP), dim3(256), 0, stream, Z, ws + OFF_PART_PCD);
  hipLaunchKernelGGL(reduce_cov_kernel, dim3(256), dim3(128), 0, stream, ws);
  hipLaunchKernelGGL(invert_kernel, dim3(2), dim3(512), 0, stream, ws);
  hipLaunchKernelGGL(attn_kernel, dim3(256), dim3(128), 0, stream, ws);
  hipLaunchKernelGGL(mb_kernel, dim3(32), dim3(256), 0, stream, ws);
  hipLaunchKernelGGL(img_final_mfma_kernel, dim3(HWSZ/128), dim3(256), 0, stream, img_in, ws, X);
  hipLaunchKernelGGL(pcd_final_kernel, dim3(NPC/16), dim3(256), 0, stream, pcd_in, ws, Z);
}

// Round 4
// 864.651 us; speedup vs baseline: 2.4854x; 1.0582x over previous
//
#include <hip/hip_runtime.h>
#include <math.h>

#define HH 480
#define WW 640
#define HWSZ (HH*WW)        // 307200
#define NPC 22432
#define IMG_SZ (128*HWSZ)   // 39321600
#define NBI 256             // gram img partial blocks
#define NBP 64              // gram pcd partial blocks
#define CHUNK_I 1200        // 256*1200 = 307200
#define CHUNK_P 351         // 64*351 = 22464 >= 22432

typedef unsigned short u16;
typedef unsigned int u32;
typedef __attribute__((ext_vector_type(8))) short bf16x8;
typedef __attribute__((ext_vector_type(4))) float f32x4;

// ws float offsets
#define OFF_SUMS_IMG 0
#define OFF_SUMS_PCD 128
#define OFF_BIAS2    256
#define OFF_COV_IMG  512
#define OFF_COV_PCD  16896
#define OFF_INV_IMG  33280
#define OFF_INV_PCD  49664
#define OFF_MT_IMG   66048
#define OFF_MT_PCD   82432
#define OFF_LWT      98816
#define OFF_PSUMS    115200      // 256*128 = 32768
#define OFF_MB       147968     // M_img bf16 [c][k]: 16384 u16 = 4096 floats
#define OFF_WT       152064     // 128*9*128 fp32 (fallback conv) = 147456
#define OFF_PART_IMG 299520     // NBI*16384 = 4194304
#define OFF_PART_PCD 4493824    // NBP*16384 = 1048576
#define OFF_WB       5542400    // 9*128*128 bf16 = 73728 floats
#define OFF_TIMG_F   5616128    // 482*642*128 bf16 = 19804416 floats
#define TIMG_PAD_W 642
#define TIMG_PX (482*642)       // 309444
#define TIMG_U16 (TIMG_PX*128)  // 39608832
#define WS_NEED_FLOATS 25420544

__device__ inline u32 pack_bf16(float a, float b) {
  u32 ua = __float_as_uint(a), ub = __float_as_uint(b);
  ua += 0x7FFFu + ((ua >> 16) & 1u);
  ub += 0x7FFFu + ((ub >> 16) & 1u);
  return (ua >> 16) | (ub & 0xFFFF0000u);
}

// ---------------- prep: fold BN into conv weights, transpose linear weights ----
__global__ void prep_kernel(const float* __restrict__ conv_w, const float* __restrict__ conv_b,
                            const float* __restrict__ gamma, const float* __restrict__ beta,
                            const float* __restrict__ mean, const float* __restrict__ var,
                            const float* __restrict__ lin_w, float* __restrict__ ws, int big) {
  int tid = blockIdx.x * blockDim.x + threadIdx.x;
  int nth = gridDim.x * blockDim.x;
  for (int oc = tid; oc < 128; oc += nth) {
    float s = gamma[oc] / sqrtf(var[oc] + 1e-5f);
    ws[OFF_BIAS2 + oc] = (conv_b[oc] - mean[oc]) * s + beta[oc];
  }
  if (big) {
    // Wb bf16 [tap][oc][ci]
    u16* Wb = (u16*)(ws + OFF_WB);
    for (int e = tid; e < 9*128*128; e += nth) {
      int ci = e & 127; int oc = (e >> 7) & 127; int tap = e >> 14;
      float s = gamma[oc] / sqrtf(var[oc] + 1e-5f);
      float v = conv_w[(oc*128 + ci)*9 + tap] * s;
      u32 u = __float_as_uint(v); u += 0x7FFFu + ((u >> 16) & 1u);
      Wb[e] = (u16)(u >> 16);
    }
  } else {
    // fp32 wT[ci][k][oc] = conv_w[oc][ci][k] * s[oc]
    for (int e = tid; e < 128*9*128; e += nth) {
      int oc = e & 127; int k = (e >> 7) % 9; int ci = e / 1152;
      float s = gamma[oc] / sqrtf(var[oc] + 1e-5f);
      ws[OFF_WT + e] = conv_w[(oc*128 + ci)*9 + k] * s;
    }
  }
  // lwT[k][c] = lin_w[c][k]
  for (int e = tid; e < 128*128; e += nth) {
    int c2 = e & 127; int k = e >> 7;
    ws[OFF_LWT + e] = lin_w[c2*128 + k];
  }
}

// ---------------- zero only Timg border (rest is fully overwritten) ------------
__global__ void timg_border_kernel(uint4* __restrict__ p) {
  int tid = blockIdx.x * blockDim.x + threadIdx.x;
  const int NB = (642*2 + 480*2);           // 2244 border pixels
  if (tid >= NB * 16) return;
  int px = tid >> 4, q = tid & 15;
  int addr;
  if (px < 642) addr = px;                                // row 0
  else if (px < 1284) addr = 481*642 + (px - 642);        // row 481
  else if (px < 1764) addr = (px - 1284 + 1) * 642;       // col 0, rows 1..480
  else addr = (px - 1764 + 1) * 642 + 641;                // col 641
  p[(size_t)addr * 16 + q] = make_uint4(0u, 0u, 0u, 0u);
}

// ---------------- img fp32 [128][480][640] -> Timg bf16 padded [482*642][128] --
__launch_bounds__(256)
__global__ void timg_kernel(const float* __restrict__ img, u16* __restrict__ Timg) {
  __shared__ float xt[64][133];
  const int b = blockIdx.x;
  const int h = b / 10, w0 = (b % 10) * 64;
  const int t = threadIdx.x;
  const int wl = t & 63, cib = t >> 6;
#pragma unroll
  for (int i = 0; i < 32; ++i) {
    int ci = cib + i*4;
    xt[wl][ci] = img[(size_t)ci*HWSZ + h*WW + w0 + wl];
  }
  __syncthreads();
  const int wp = t >> 2, c0 = (t & 3) * 32;
  u32 out[16];
#pragma unroll
  for (int j = 0; j < 16; ++j) {
    float a = xt[wp][c0 + 2*j], bb = xt[wp][c0 + 2*j + 1];
    out[j] = pack_bf16(a, bb);
  }
  u16* dst = Timg + ((size_t)(h+1)*TIMG_PAD_W + (w0 + 1 + wp)) * 128 + c0;
#pragma unroll
  for (int q = 0; q < 4; ++q)
    *(uint4*)(dst + q*8) = make_uint4(out[q*4], out[q*4+1], out[q*4+2], out[q*4+3]);
}

// ---------------- conv v3: LDS-staged 9-tap implicit GEMM, bf16 MFMA -----------
// block: 256 thr (4 waves), output 2 rows x 64 cols x 128 oc
// LDS region: 4 rows x 66 cols x 64 ci (half) bf16, XOR-swizzled = 33792 B
#define REG_ROWS 4
#define REG_COLS 66
#define REG_PX (REG_ROWS*REG_COLS)   // 264
__launch_bounds__(256, 3)
__global__ void conv_mfma2_kernel(const u16* __restrict__ Timg,
                                  const u16* __restrict__ Wb,
                                  const float* __restrict__ ws,
                                  float* __restrict__ X) {
  __shared__ __align__(16) u16 reg_lds[REG_PX * 64];   // 33792 B
  const int b = blockIdx.x;
  const int h0 = (b / 10) * 2;
  const int w0 = (b % 10) * 64;
  const int t = threadIdx.x;
  const int wv = t >> 6, l = t & 63;
  const int n_lane = l & 15, k_lane = l >> 4;
  const int ocg = wv >> 1;          // oc group (0/1): 64 oc
  const int rw = wv & 1;            // output row within tile

  f32x4 acc[4][4];
#pragma unroll
  for (int mt = 0; mt < 4; ++mt)
#pragma unroll
    for (int nt = 0; nt < 4; ++nt) acc[mt][nt] = (f32x4){0.f,0.f,0.f,0.f};

#pragma unroll 1
  for (int half = 0; half < 2; ++half) {
    const int ci0 = half * 64;
    __syncthreads();
    // stage region: 264 px x 64 ci bf16, phys 16B-unit j holds logical unit j^(c&7)
    for (int e = t; e < REG_PX * 8; e += 256) {
      int px = e >> 3, j = e & 7;
      int r = px / REG_COLS, c = px - r * REG_COLS;
      const u16* src = Timg + (size_t)(h0 + r) * (TIMG_PAD_W * 128)
                     + (w0 + c) * 128 + ci0 + ((j ^ (c & 7)) * 8);
      *(uint4*)((char*)reg_lds + px * 128 + j * 16) = *(const uint4*)src;
    }
    __syncthreads();
#pragma unroll 1
    for (int tap = 0; tap < 9; ++tap) {
      const int kh = (tap * 11) >> 5;       // tap/3
      const int kw = tap - kh * 3;
      const int swz4 = ((n_lane + kw) & 7) << 4;
      const int pxb = (rw + kh) * REG_COLS + n_lane + kw;
      const u16* wtap = Wb + tap * 16384 + (ocg * 64 + n_lane) * 128 + ci0 + k_lane * 8;
#pragma unroll
      for (int s = 0; s < 2; ++s) {
        bf16x8 Af[4], Bf[4];
#pragma unroll
        for (int mt = 0; mt < 4; ++mt)
          Af[mt] = *(const bf16x8*)(wtap + mt * 2048 + s * 32);
#pragma unroll
        for (int nt = 0; nt < 4; ++nt)
          Bf[nt] = *(const bf16x8*)((char*)reg_lds + (pxb + nt * 16) * 128
                                    + ((s * 64 + k_lane * 16) ^ swz4));
#pragma unroll
        for (int mt = 0; mt < 4; ++mt)
#pragma unroll
          for (int nt = 0; nt < 4; ++nt)
            acc[mt][nt] = __builtin_amdgcn_mfma_f32_16x16x32_bf16(Af[mt], Bf[nt], acc[mt][nt], 0, 0, 0);
      }
    }
  }
  // epilogue: bias + ReLU; D layout: col(px)=lane&15, row(oc)=k_lane*4+rr
  const float* bias = ws + OFF_BIAS2;
  const int pxw = (h0 + rw) * WW + w0 + n_lane;
#pragma unroll
  for (int mt = 0; mt < 4; ++mt) {
    f32x4 bv = *(const f32x4*)(bias + ocg * 64 + mt * 16 + k_lane * 4);
#pragma unroll
    for (int nt = 0; nt < 4; ++nt) {
#pragma unroll
      for (int rr = 0; rr < 4; ++rr) {
        int oc = ocg * 64 + mt * 16 + k_lane * 4 + rr;
        float v = acc[mt][nt][rr] + bv[rr];
        X[(size_t)oc * HWSZ + pxw + nt * 16] = fmaxf(v, 0.f);
      }
    }
  }
}

// ---------------- fp32 fallback conv -------------------------------------------
__launch_bounds__(256)
__global__ void conv_kernel(const float* __restrict__ img,
                            const float* __restrict__ ws,
                            float* __restrict__ outX) {
  __shared__ __align__(16) float xs[8][10][20];
  __shared__ __align__(16) float wsm[8][9][64];
  const int b = blockIdx.x;
  const int oc0 = (b & 1) * 64;
  const int sidx = b >> 1;
  const int h0 = (sidx / 40) * 8;
  const int w0 = (sidx % 40) * 16;
  const int t = threadIdx.x;
  const int oc_t = t & 15;
  const int px_t = t >> 4;
  const int ph = px_t >> 1;
  const int pw0 = (px_t & 1) * 8;
  float acc[4][8];
#pragma unroll
  for (int o = 0; o < 4; o++)
#pragma unroll
    for (int m = 0; m < 8; m++) acc[o][m] = 0.f;
  const float* wT = ws + OFF_WT;
  for (int ci0 = 0; ci0 < 128; ci0 += 8) {
    __syncthreads();
    for (int e = t; e < 1440; e += 256) {
      int ci = e / 180; int rem = e - ci*180; int r = rem / 18; int cc2 = rem - r*18;
      int gh = h0 + r - 1, gw = w0 + cc2 - 1;
      float v = 0.f;
      if ((unsigned)gh < (unsigned)HH && (unsigned)gw < (unsigned)WW)
        v = img[(ci0+ci)*HWSZ + gh*WW + gw];
      xs[ci][r][cc2] = v;
    }
    for (int e = t; e < 4608; e += 256) {
      int oc = e & 63; int k = (e >> 6) % 9; int ci = e / 576;
      wsm[ci][k][oc] = wT[((ci0+ci)*9 + k)*128 + oc0 + oc];
    }
    __syncthreads();
#pragma unroll
    for (int ci = 0; ci < 8; ci++) {
#pragma unroll
      for (int kh = 0; kh < 3; kh++) {
        float x10[10];
        float4 xa = *(const float4*)&xs[ci][ph+kh][pw0];
        float4 xb = *(const float4*)&xs[ci][ph+kh][pw0+4];
        x10[0]=xa.x; x10[1]=xa.y; x10[2]=xa.z; x10[3]=xa.w;
        x10[4]=xb.x; x10[5]=xb.y; x10[6]=xb.z; x10[7]=xb.w;
        x10[8]=xs[ci][ph+kh][pw0+8]; x10[9]=xs[ci][ph+kh][pw0+9];
#pragma unroll
        for (int kw = 0; kw < 3; kw++) {
          float4 wv = *(const float4*)&wsm[ci][kh*3+kw][oc_t*4];
#pragma unroll
          for (int m = 0; m < 8; m++) {
            float xv = x10[kw+m];
            acc[0][m] += wv.x*xv; acc[1][m] += wv.y*xv;
            acc[2][m] += wv.z*xv; acc[3][m] += wv.w*xv;
          }
        }
      }
    }
  }
#pragma unroll
  for (int o = 0; o < 4; o++) {
    int oc = oc0 + oc_t*4 + o;
    float bias = ws[OFF_BIAS2 + oc];
    float4 r0, r1;
    r0.x = fmaxf(acc[o][0]+bias, 0.f); r0.y = fmaxf(acc[o][1]+bias, 0.f);
    r0.z = fmaxf(acc[o][2]+bias, 0.f); r0.w = fmaxf(acc[o][3]+bias, 0.f);
    r1.x = fmaxf(acc[o][4]+bias, 0.f); r1.y = fmaxf(acc[o][5]+bias, 0.f);
    r1.z = fmaxf(acc[o][6]+bias, 0.f); r1.w = fmaxf(acc[o][7]+bias, 0.f);
    float* dst = outX + (size_t)oc*HWSZ + (h0+ph)*WW + w0 + pw0;
    *(float4*)dst = r0; *(float4*)(dst+4) = r1;
  }
}

// ---------------- linear + ReLU -> Z -------------------------------------------
__launch_bounds__(256)
__global__ void linear_kernel(const float* __restrict__ pcd,
                              const float* __restrict__ ws,
                              const float* __restrict__ lin_b,
                              float* __restrict__ Z) {
  __shared__ __align__(16) float Mt[128][132];
  __shared__ __align__(16) float zs[16][132];
  const int b = blockIdx.x, t = threadIdx.x;
  const int n0 = b * 16;
#pragma unroll
  for (int i = 0; i < 16; i++) {
    int idx = t + i*256; int r = idx >> 5; int c4 = (idx & 31)*4;
    *(float4*)&Mt[r][c4] = *(const float4*)&ws[OFF_LWT + r*128 + c4];
  }
#pragma unroll
  for (int i = 0; i < 2; i++) {
    int idx = t + i*256; int r = idx >> 5; int c4 = (idx & 31)*4;
    *(float4*)&zs[r][c4] = *(const float4*)&pcd[(size_t)(n0+r)*128 + c4];
  }
  __syncthreads();
  const int nl = t & 15;
  const int c0 = (t >> 4) * 8;
  float acc[8];
#pragma unroll
  for (int q = 0; q < 8; q++) acc[q] = 0.f;
#pragma unroll 8
  for (int k = 0; k < 128; k++) {
    float z = zs[nl][k];
    float4 wa = *(const float4*)&Mt[k][c0];
    float4 wb = *(const float4*)&Mt[k][c0+4];
    acc[0]+=z*wa.x; acc[1]+=z*wa.y; acc[2]+=z*wa.z; acc[3]+=z*wa.w;
    acc[4]+=z*wb.x; acc[5]+=z*wb.y; acc[6]+=z*wb.z; acc[7]+=z*wb.w;
  }
  float4 ba = *(const float4*)&lin_b[c0];
  float4 bb = *(const float4*)&lin_b[c0+4];
  float4 r0, r1;
  r0.x = fmaxf(acc[0]+ba.x,0.f); r0.y = fmaxf(acc[1]+ba.y,0.f);
  r0.z = fmaxf(acc[2]+ba.z,0.f); r0.w = fmaxf(acc[3]+ba.w,0.f);
  r1.x = fmaxf(acc[4]+bb.x,0.f); r1.y = fmaxf(acc[5]+bb.y,0.f);
  r1.z = fmaxf(acc[6]+bb.z,0.f); r1.w = fmaxf(acc[7]+bb.w,0.f);
  float* dst = Z + (size_t)(n0+nl)*128 + c0;
  *(float4*)dst = r0; *(float4*)(dst+4) = r1;
}

// ---------------- pcd channel sums ---------------------------------------------
__launch_bounds__(256)
__global__ void sums_pcd_kernel(const float* __restrict__ Z, float* __restrict__ ws) {
  const int c = blockIdx.x, t = threadIdx.x;
  float s = 0.f;
  for (int n = t; n < NPC; n += 256) s += Z[(size_t)n*128 + c];
  __shared__ float red[256];
  red[t] = s; __syncthreads();
  for (int s2 = 128; s2 > 0; s2 >>= 1) { if (t < s2) red[t] += red[t+s2]; __syncthreads(); }
  if (t == 0) ws[OFF_SUMS_PCD + c] = red[0];
}

// ---------------- gram img via MFMA (bf16 LDS tile, fused channel sums) --------
__launch_bounds__(256)
__global__ void gram_img_mfma_kernel(const float* __restrict__ X,
                                     float* __restrict__ part,
                                     float* __restrict__ psums) {
  __shared__ __align__(16) u16 tile[128*64];   // [c][px64] bf16, XOR-swizzled
  const int b = blockIdx.x, t = threadIdx.x;
  const int px0 = b * CHUNK_I;
  const int pg = t & 15;            // staging: px granule (4 px)
  const int g0 = t >> 4;            // staging: channel group base (16 c per pass)
  const int wv = t >> 6, l = t & 63;
  const int i0 = (wv >> 1) * 64, j0 = (wv & 1) * 64;
  const int row16 = l & 15, kq = l >> 4;
  float csum[8];
#pragma unroll
  for (int q = 0; q < 8; ++q) csum[q] = 0.f;
  f32x4 acc[4][4];
#pragma unroll
  for (int a = 0; a < 4; ++a)
#pragma unroll
    for (int q = 0; q < 4; ++q) acc[a][q] = (f32x4){0.f,0.f,0.f,0.f};

  for (int ti = 0; ti < 19; ++ti) {
    const int plg = ti*64 + pg*4;   // local px of this granule
    float4 v[8];
    if (ti < 18) {
#pragma unroll
      for (int cc = 0; cc < 8; ++cc) {
        int c = g0 + cc*16;
        v[cc] = *(const float4*)(X + (size_t)c*HWSZ + px0 + plg);
      }
    } else {
#pragma unroll
      for (int cc = 0; cc < 8; ++cc) {
        int c = g0 + cc*16;
        const float* src = X + (size_t)c*HWSZ + px0;
#pragma unroll
        for (int j = 0; j < 4; ++j) {
          int p = plg + j;
          ((float*)&v[cc])[j] = (p < CHUNK_I) ? src[p] : 0.f;
        }
      }
    }
    __syncthreads();   // previous tile fully consumed
#pragma unroll
    for (int cc = 0; cc < 8; ++cc) {
      int c = g0 + cc*16;
      csum[cc] += v[cc].x + v[cc].y + v[cc].z + v[cc].w;
      u32 w0 = pack_bf16(v[cc].x, v[cc].y);
      u32 w1 = pack_bf16(v[cc].z, v[cc].w);
      *(uint2*)((char*)tile + c*128 + ((pg*8) ^ ((c & 7) << 4))) = make_uint2(w0, w1);
    }
    __syncthreads();
#pragma unroll
    for (int f = 0; f < 2; ++f) {
      bf16x8 Af[4], Bf[4];
#pragma unroll
      for (int mt = 0; mt < 4; ++mt) {
        int c = i0 + mt*16 + row16;
        Af[mt] = *(const bf16x8*)((char*)tile + c*128 + ((f*64 + kq*16) ^ ((c & 7) << 4)));
      }
#pragma unroll
      for (int nt = 0; nt < 4; ++nt) {
        int c = j0 + nt*16 + row16;
        Bf[nt] = *(const bf16x8*)((char*)tile + c*128 + ((f*64 + kq*16) ^ ((c & 7) << 4)));
      }
#pragma unroll
      for (int mt = 0; mt < 4; ++mt)
#pragma unroll
        for (int nt = 0; nt < 4; ++nt)
          acc[mt][nt] = __builtin_amdgcn_mfma_f32_16x16x32_bf16(Af[mt], Bf[nt], acc[mt][nt], 0, 0, 0);
    }
  }
#pragma unroll
  for (int cc = 0; cc < 8; ++cc) {
    float s = csum[cc];
    s += __shfl_xor(s, 1, 64);
    s += __shfl_xor(s, 2, 64);
    s += __shfl_xor(s, 4, 64);
    s += __shfl_xor(s, 8, 64);
    if (pg == 0) psums[b*128 + g0 + cc*16] = s;
  }
  float* dst = part + (size_t)b*16384;
#pragma unroll
  for (int mt = 0; mt < 4; ++mt)
#pragma unroll
    for (int nt = 0; nt < 4; ++nt) {
#pragma unroll
      for (int r = 0; r < 4; ++r) {
        int i = i0 + mt*16 + kq*4 + r;
        int j = j0 + nt*16 + row16;
        dst[i*128 + j] = acc[mt][nt][r];
      }
    }
}

// ---------------- reduce img psums -> SUMS_IMG ---------------------------------
__global__ void psums_reduce_kernel(float* __restrict__ ws) {
  int t = threadIdx.x;  // 128
  float s = 0.f;
  const float* ps = ws + OFF_PSUMS;
  for (int b = 0; b < NBI; ++b) s += ps[b*128 + t];
  ws[OFF_SUMS_IMG + t] = s;
}

// ---------------- gram pcd (fp32) ----------------------------------------------
__launch_bounds__(256)
__global__ void gram_pcd_kernel(const float* __restrict__ Z, float* __restrict__ part) {
  __shared__ __align__(16) float zt[64][132];
  const int b = blockIdx.x, t = threadIdx.x;
  const int n0 = b * CHUNK_P;
  const int i0 = (t >> 4) * 8, j0 = (t & 15) * 8;
  float acc[8][8];
#pragma unroll
  for (int a = 0; a < 8; a++)
#pragma unroll
    for (int q = 0; q < 8; q++) acc[a][q] = 0.f;
  for (int tile = 0; tile < 6; tile++) {
    __syncthreads();
#pragma unroll
    for (int i = 0; i < 8; i++) {
      int idx = t + i*256; int r = idx >> 5; int c4 = (idx & 31)*4;
      int lrow = tile*64 + r;
      int n = n0 + lrow;
      float4 v = {0.f,0.f,0.f,0.f};
      if (lrow < CHUNK_P && n < NPC) v = *(const float4*)&Z[(size_t)n*128 + c4];
      *(float4*)&zt[r][c4] = v;
    }
    __syncthreads();
#pragma unroll 4
    for (int n = 0; n < 64; n++) {
      float4 a0 = *(const float4*)&zt[n][i0];
      float4 a1 = *(const float4*)&zt[n][i0+4];
      float4 b0 = *(const float4*)&zt[n][j0];
      float4 b1 = *(const float4*)&zt[n][j0+4];
      float av[8] = {a0.x,a0.y,a0.z,a0.w,a1.x,a1.y,a1.z,a1.w};
      float bv[8] = {b0.x,b0.y,b0.z,b0.w,b1.x,b1.y,b1.z,b1.w};
#pragma unroll
      for (int a = 0; a < 8; a++)
#pragma unroll
        for (int q = 0; q < 8; q++) acc[a][q] += av[a]*bv[q];
    }
  }
  float* dst = part + (size_t)b*16384;
#pragma unroll
  for (int a = 0; a < 8; a++) {
    float4 w0v = {acc[a][0],acc[a][1],acc[a][2],acc[a][3]};
    float4 w1v = {acc[a][4],acc[a][5],acc[a][6],acc[a][7]};
    *(float4*)&dst[(i0+a)*128 + j0] = w0v;
    *(float4*)&dst[(i0+a)*128 + j0 + 4] = w1v;
  }
}

// ---------------- reduce partials -> cov ---------------------------------------
__launch_bounds__(128)
__global__ void reduce_cov_kernel(float* __restrict__ ws) {
  const int b = blockIdx.x, t = threadIdx.x;
  const bool isimg = (b < 128);
  const int i = isimg ? b : b - 128;
  const int nparts = isimg ? NBI : NBP;
  const float* part = ws + (isimg ? OFF_PART_IMG : OFF_PART_PCD);
  float g = 0.f;
  for (int p = 0; p < nparts; p++) g += part[(size_t)p*16384 + i*128 + t];
  float Si = ws[(isimg ? OFF_SUMS_IMG : OFF_SUMS_PCD) + i];
  float Sj = ws[(isimg ? OFF_SUMS_IMG : OFF_SUMS_PCD) + t];
  float n = isimg ? (float)HWSZ : (float)NPC;
  float cov = (g - Si*Sj/n) / (n - 1.f);
  ws[(isimg ? OFF_COV_IMG : OFF_COV_PCD) + i*128 + t] = cov;
}

// ---------------- in-place Gauss-Jordan inverse of (cov + 1e-6 I) --------------
__launch_bounds__(512)
__global__ void invert_kernel(float* __restrict__ ws) {
  __shared__ __align__(16) float A[128][132];
  const int b = blockIdx.x, t = threadIdx.x;
  const float* src = ws + (b == 0 ? OFF_COV_IMG : OFF_COV_PCD);
  float* dst = ws + (b == 0 ? OFF_INV_IMG : OFF_INV_PCD);
  for (int i = 0; i < 32; i++) {
    int idx = t + i*512; int r = idx >> 7; int cc = idx & 127;
    A[r][cc] = src[idx] + (r == cc ? 1e-6f : 0.f);
  }
  const int row = t >> 2;
  const int cbase = (t & 3) * 32;
  for (int k = 0; k < 128; k++) {
    __syncthreads();
    float ip = 1.f / A[k][k];
    float f = (row != k) ? A[row][k] : 0.f;
    __syncthreads();
    if (t < 128) A[k][t] = (t == k) ? ip : A[k][t] * ip;
    __syncthreads();
    if (row != k) {
#pragma unroll
      for (int cc = 0; cc < 8; cc++) {
        int c4 = cbase + cc*4;
        float4 v = *(const float4*)&A[row][c4];
        float4 p = *(const float4*)&A[k][c4];
        v.x -= f*p.x; v.y -= f*p.y; v.z -= f*p.z; v.w -= f*p.w;
        if (k >= c4 && k < c4+4) {
          float nv = -f*ip;
          if (k == c4) v.x = nv; else if (k == c4+1) v.y = nv;
          else if (k == c4+2) v.z = nv; else v.w = nv;
        }
        *(float4*)&A[row][c4] = v;
      }
    }
  }
  __syncthreads();
  for (int i = 0; i < 32; i++) {
    int idx = t + i*512; int r = idx >> 7; int cc = idx & 127;
    dst[idx] = A[r][cc];
  }
}

// ---------------- attention rows -> transposed mix matrices M^T ----------------
__launch_bounds__(128)
__global__ void attn_kernel(float* __restrict__ ws) {
  const int b = blockIdx.x, j = threadIdx.x;
  const bool isimg = (b < 128);
  const int i = isimg ? b : b - 128;
  const float* rowA = ws + (isimg ? OFF_COV_PCD : OFF_COV_IMG) + i*128;
  const float* matA = ws + (isimg ? OFF_INV_IMG : OFF_INV_PCD);
  const float* rowB = ws + (isimg ? OFF_COV_IMG : OFF_COV_PCD) + i*128;
  const float* matB = ws + (isimg ? OFF_COV_IMG : OFF_COV_PCD);
  __shared__ float rA[128], rB[128], red[128];
  rA[j] = rowA[j]; rB[j] = rowB[j];
  __syncthreads();
  float dA = 0.f, dB = 0.f;
#pragma unroll 8
  for (int k = 0; k < 128; k += 4) {
    float4 va = *(const float4*)&matA[j*128 + k];
    float4 vb = *(const float4*)&matB[j*128 + k];
    dA += rA[k]*va.x + rA[k+1]*va.y + rA[k+2]*va.z + rA[k+3]*va.w;
    dB += rB[k]*vb.x + rB[k+1]*vb.y + rB[k+2]*vb.z + rB[k+3]*vb.w;
  }
  dA *= 0.0078125f; dB *= 0.0078125f;
  red[j] = dA; __syncthreads();
  for (int s2 = 64; s2 > 0; s2 >>= 1) { if (j < s2) red[j] = fmaxf(red[j], red[j+s2]); __syncthreads(); }
  float mA = red[0]; __syncthreads();
  float eA = expf(dA - mA);
  red[j] = eA; __syncthreads();
  for (int s2 = 64; s2 > 0; s2 >>= 1) { if (j < s2) red[j] += red[j+s2]; __syncthreads(); }
  float sA = red[0]; __syncthreads();
  red[j] = dB; __syncthreads();
  for (int s2 = 64; s2 > 0; s2 >>= 1) { if (j < s2) red[j] = fmaxf(red[j], red[j+s2]); __syncthreads(); }
  float mB = red[0]; __syncthreads();
  float eB = expf(dB - mB);
  red[j] = eB; __syncthreads();
  for (int s2 = 64; s2 > 0; s2 >>= 1) { if (j < s2) red[j] += red[j+s2]; __syncthreads(); }
  float sB = red[0]; __syncthreads();
  float m = 0.1f * (eA/sA + eB/sB);
  float* MT = ws + (isimg ? OFF_MT_IMG : OFF_MT_PCD);
  MT[j*128 + i] = m;
}

// ---------------- M_img fp32 [k][c] -> Mb bf16 [c][k] --------------------------
__global__ void mb_kernel(float* __restrict__ ws) {
  int e = blockIdx.x * 256 + threadIdx.x;   // 8192 threads
  int c = e >> 6, kp = e & 63;
  float lo = ws[OFF_MT_IMG + (2*kp)*128 + c];
  float hi = ws[OFF_MT_IMG + (2*kp+1)*128 + c];
  ((u32*)(ws + OFF_MB))[c*64 + kp] = pack_bf16(lo, hi);
}

// ---------------- img final via MFMA: io = M@io + 0.8*img (in place) -----------
__launch_bounds__(256)
__global__ void img_final_mfma_kernel(const float* __restrict__ img_in,
                                      const float* __restrict__ ws,
                                      float* __restrict__ io) {
  __shared__ __align__(16) u16 bt[128*128];   // [px][c] bf16, XOR-swizzled, 32KB
  const int blk = blockIdx.x, t = threadIdx.x;
  const int px0 = blk * 128;
  const int pxg = (t & 31) * 4;     // px granule
  const int cp0 = t >> 5;           // channel-pair base (0..7)
#pragma unroll
  for (int cc = 0; cc < 8; ++cc) {
    int cpair = cp0 + cc*8;
    const float* s0 = io + (size_t)(2*cpair)*HWSZ + px0 + pxg;
    float4 a = *(const float4*)s0;
    float4 b4 = *(const float4*)(s0 + HWSZ);
#pragma unroll
    for (int j = 0; j < 4; ++j) {
      int pxl = pxg + j;
      *(u32*)((char*)bt + pxl*256 + ((cpair*4) ^ ((pxl & 7) << 4))) =
          pack_bf16(((const float*)&a)[j], ((const float*)&b4)[j]);
    }
  }
  __syncthreads();
  const int wv = t >> 6, l = t & 63;
  const int i0 = (wv >> 1) * 64, j0 = (wv & 1) * 64;
  const int row16 = l & 15, kq = l >> 4;
  const u16* Mb = (const u16*)(ws + OFF_MB);
  f32x4 acc[4][4];
#pragma unroll
  for (int a = 0; a < 4; ++a)
#pragma unroll
    for (int q = 0; q < 4; ++q) acc[a][q] = (f32x4){0.f,0.f,0.f,0.f};
#pragma unroll
  for (int f = 0; f < 4; ++f) {
    bf16x8 Bf[4], Am[4];
#pragma unroll
    for (int nt = 0; nt < 4; ++nt) {
      int pxl = j0 + nt*16 + row16;
      Bf[nt] = *(const bf16x8*)((char*)bt + pxl*256 + ((f*64 + kq*16) ^ ((pxl & 7) << 4)));
    }
#pragma unroll
    for (int mt = 0; mt < 4; ++mt) {
      int c = i0 + mt*16 + row16;
      Am[mt] = *(const bf16x8*)((const char*)Mb + c*256 + f*64 + kq*16);
    }
#pragma unroll
    for (int mt = 0; mt < 4; ++mt)
#pragma unroll
      for (int nt = 0; nt < 4; ++nt)
        acc[mt][nt] = __builtin_amdgcn_mfma_f32_16x16x32_bf16(Am[mt], Bf[nt], acc[mt][nt], 0, 0, 0);
  }
#pragma unroll
  for (int mt = 0; mt < 4; ++mt)
#pragma unroll
    for (int nt = 0; nt < 4; ++nt) {
      int pxl = j0 + nt*16 + row16;
#pragma unroll
      for (int r = 0; r < 4; ++r) {
        int c = i0 + mt*16 + kq*4 + r;
        size_t off = (size_t)c*HWSZ + px0 + pxl;
        io[off] = acc[mt][nt][r] + 0.8f*img_in[off];
      }
    }
}

// ---------------- pcd final: Z = Z @ M_pcd^T + 0.8*pcd (in place) --------------
__launch_bounds__(256)
__global__ void pcd_final_kernel(const float* __restrict__ pcd_in,
                                 const float* __restrict__ ws,
                                 float* __restrict__ Z) {
  __shared__ __align__(16) float Mt[128][132];
  __shared__ __align__(16) float zs[16][132];
  const int b = blockIdx.x, t = threadIdx.x;
  const int n0 = b * 16;
#pragma unroll
  for (int i = 0; i < 16; i++) {
    int idx = t + i*256; int r = idx >> 5; int c4 = (idx & 31)*4;
    *(float4*)&Mt[r][c4] = *(const float4*)&ws[OFF_MT_PCD + r*128 + c4];
  }
#pragma unroll
  for (int i = 0; i < 2; i++) {
    int idx = t + i*256; int r = idx >> 5; int c4 = (idx & 31)*4;
    *(float4*)&zs[r][c4] = *(const float4*)&Z[(size_t)(n0+r)*128 + c4];
  }
  __syncthreads();
  const int nl = t & 15;
  const int c0 = (t >> 4) * 8;
  float acc[8];
#pragma unroll
  for (int q = 0; q < 8; q++) acc[q] = 0.f;
#pragma unroll 8
  for (int k = 0; k < 128; k++) {
    float z = zs[nl][k];
    float4 wa = *(const float4*)&Mt[k][c0];
    float4 wb = *(const float4*)&Mt[k][c0+4];
    acc[0]+=z*wa.x; acc[1]+=z*wa.y; acc[2]+=z*wa.z; acc[3]+=z*wa.w;
    acc[4]+=z*wb.x; acc[5]+=z*wb.y; acc[6]+=z*wb.z; acc[7]+=z*wb.w;
  }
  size_t off = (size_t)(n0+nl)*128 + c0;
  float4 pa = *(const float4*)&pcd_in[off];
  float4 pb = *(const float4*)&pcd_in[off+4];
  float4 r0, r1;
  r0.x = acc[0] + 0.8f*pa.x; r0.y = acc[1] + 0.8f*pa.y;
  r0.z = acc[2] + 0.8f*pa.z; r0.w = acc[3] + 0.8f*pa.w;
  r1.x = acc[4] + 0.8f*pb.x; r1.y = acc[5] + 0.8f*pb.y;
  r1.z = acc[6] + 0.8f*pb.z; r1.w = acc[7] + 0.8f*pb.w;
  *(float4*)&Z[off] = r0; *(float4*)&Z[off+4] = r1;
}

extern "C" void kernel_launch(void* const* d_in, const int* in_sizes, int n_in,
                              void* d_out, int out_size, void* d_ws, size_t ws_size,
                              hipStream_t stream) {
  (void)in_sizes; (void)n_in; (void)out_size;
  const float* img_in = (const float*)d_in[0];
  const float* pcd_in = (const float*)d_in[1];
  const float* conv_w = (const float*)d_in[2];
  const float* conv_b = (const float*)d_in[3];
  const float* gamma  = (const float*)d_in[4];
  const float* beta   = (const float*)d_in[5];
  const float* mean   = (const float*)d_in[6];
  const float* var    = (const float*)d_in[7];
  const float* lin_w  = (const float*)d_in[8];
  const float* lin_b  = (const float*)d_in[9];
  float* out = (float*)d_out;
  float* X = out;            // [128][307200] conv output, transformed in place
  float* Z = out + IMG_SZ;   // [22432][128] linear output, transformed in place
  float* ws = (float*)d_ws;
  const int big = (ws_size >= (size_t)WS_NEED_FLOATS * 4) ? 1 : 0;

  hipLaunchKernelGGL(prep_kernel, dim3(64), dim3(256), 0, stream,
                     conv_w, conv_b, gamma, beta, mean, var, lin_w, ws, big);
  if (big) {
    u16* Timg = (u16*)(ws + OFF_TIMG_F);
    u16* Wb = (u16*)(ws + OFF_WB);
    hipLaunchKernelGGL(timg_border_kernel, dim3(141), dim3(256), 0, stream, (uint4*)Timg);
    hipLaunchKernelGGL(timg_kernel, dim3(4800), dim3(256), 0, stream, img_in, Timg);
    hipLaunchKernelGGL(conv_mfma2_kernel, dim3(2400), dim3(256), 0, stream, Timg, Wb, ws, X);
  } else {
    hipLaunchKernelGGL(conv_kernel, dim3(4800), dim3(256), 0, stream, img_in, ws, X);
  }
  hipLaunchKernelGGL(linear_kernel, dim3(NPC/16), dim3(256), 0, stream, pcd_in, ws, lin_b, Z);
  hipLaunchKernelGGL(gram_img_mfma_kernel, dim3(NBI), dim3(256), 0, stream,
                     X, ws + OFF_PART_IMG, ws + OFF_PSUMS);
  hipLaunchKernelGGL(psums_reduce_kernel, dim3(1), dim3(128), 0, stream, ws);
  hipLaunchKernelGGL(sums_pcd_kernel, dim3(128), dim3(256), 0, stream, Z, ws);
  hipLaunchKernelGGL(gram_pcd_kernel, dim3(NBP), dim3(256), 0, stream, Z, ws + OFF_PART_PCD);
  hipLaunchKernelGGL(reduce_cov_kernel, dim3(256), dim3(128), 0, stream, ws);
  hipLaunchKernelGGL(invert_kernel, dim3(2), dim3(512), 0, stream, ws);
  hipLaunchKernelGGL(attn_kernel, dim3(256), dim3(128), 0, stream, ws);
  hipLaunchKernelGGL(mb_kernel, dim3(32), dim3(256), 0, stream, ws);
  hipLaunchKernelGGL(img_final_mfma_kernel, dim3(HWSZ/128), dim3(256), 0, stream, img_in, ws, X);
  hipLaunchKernelGGL(pcd_final_kernel, dim3(NPC/16), dim3(256), 0, stream, pcd_in, ws, Z);
}

// Round 5
// 772.858 us; speedup vs baseline: 2.7806x; 1.1188x over previous
//
#include <hip/hip_runtime.h>
#include <math.h>

#define HH 480
#define WW 640
#define HWSZ (HH*WW)        // 307200
#define NPC 22432
#define IMG_SZ (128*HWSZ)   // 39321600
#define NBI 256             // gram img partial blocks
#define NBP 64              // gram pcd partial blocks
#define CHUNK_I 1200        // 256*1200 = 307200
#define CHUNK_P 351         // 64*351 = 22464 >= 22432

typedef unsigned short u16;
typedef unsigned int u32;
typedef __attribute__((ext_vector_type(8))) short bf16x8;
typedef __attribute__((ext_vector_type(4))) float f32x4;

// ws float offsets
#define OFF_SUMS_IMG 0
#define OFF_SUMS_PCD 128
#define OFF_BIAS2    256
#define OFF_COV_IMG  512
#define OFF_COV_PCD  16896
#define OFF_INV_IMG  33280
#define OFF_INV_PCD  49664
#define OFF_MT_IMG   66048
#define OFF_MT_PCD   82432
#define OFF_LWT      98816
#define OFF_PSUMS    115200     // 256*128 = 32768
#define OFF_MB       147968     // M_img bf16 fragments: 16384 u16 = 4096 floats
#define OFF_WT       152064     // 128*9*128 fp32 (fallback conv) = 147456
#define OFF_PART_IMG 299520     // NBI*16384 = 4194304
#define OFF_PART_PCD 4493824    // NBP*16384 = 1048576
#define OFF_WB       5542400    // 9*128*128 bf16 = 73728 floats (fragment layout)
#define OFF_TIMG_F   5616128    // 482*642*128 bf16 = 19804416 floats
#define TIMG_PAD_W 642
#define TIMG_PX (482*642)       // 309444
#define TIMG_U16 (TIMG_PX*128)  // 39608832
#define WS_NEED_FLOATS 25420544

__device__ inline u32 pack_bf16(float a, float b) {
  u32 ua = __float_as_uint(a), ub = __float_as_uint(b);
  ua += 0x7FFFu + ((ua >> 16) & 1u);
  ub += 0x7FFFu + ((ub >> 16) & 1u);
  return (ua >> 16) | (ub & 0xFFFF0000u);
}
__device__ inline u16 to_bf16(float v) {
  u32 u = __float_as_uint(v); u += 0x7FFFu + ((u >> 16) & 1u);
  return (u16)(u >> 16);
}

// ---------------- prep: fold BN into conv weights (fragment layout) ------------
// Wf fragment id fid = (tap*4 + ci32)*8 + ob ; lane l holds oc=ob*16+(l&15),
// ci = ci32*32 + (l>>4)*8 + j  (j=0..7). 1024B per fragment, wave-contiguous.
__global__ void prep_kernel(const float* __restrict__ conv_w, const float* __restrict__ conv_b,
                            const float* __restrict__ gamma, const float* __restrict__ beta,
                            const float* __restrict__ mean, const float* __restrict__ var,
                            const float* __restrict__ lin_w, float* __restrict__ ws, int big) {
  int tid = blockIdx.x * blockDim.x + threadIdx.x;
  int nth = gridDim.x * blockDim.x;
  for (int oc = tid; oc < 128; oc += nth) {
    float s = gamma[oc] / sqrtf(var[oc] + 1e-5f);
    ws[OFF_BIAS2 + oc] = (conv_b[oc] - mean[oc]) * s + beta[oc];
  }
  if (big) {
    u16* Wf = (u16*)(ws + OFF_WB);
    for (int e = tid; e < 9*128*128; e += nth) {
      int j = e & 7, l = (e >> 3) & 63, ob = (e >> 9) & 7;
      int ci32 = (e >> 12) & 3, tap = e >> 14;
      int oc = ob*16 + (l & 15);
      int ci = ci32*32 + ((l >> 4) & 3)*8 + j;
      float s = gamma[oc] / sqrtf(var[oc] + 1e-5f);
      Wf[e] = to_bf16(conv_w[(oc*128 + ci)*9 + tap] * s);
    }
  } else {
    for (int e = tid; e < 128*9*128; e += nth) {
      int oc = e & 127; int k = (e >> 7) % 9; int ci = e / 1152;
      float s = gamma[oc] / sqrtf(var[oc] + 1e-5f);
      ws[OFF_WT + e] = conv_w[(oc*128 + ci)*9 + k] * s;
    }
  }
  for (int e = tid; e < 128*128; e += nth) {
    int c2 = e & 127; int k = e >> 7;
    ws[OFF_LWT + e] = lin_w[c2*128 + k];
  }
}

// ---------------- img fp32 -> Timg bf16 padded [482*642][128] (+border zero) ---
__launch_bounds__(256)
__global__ void timg_kernel(const float* __restrict__ img, u16* __restrict__ Timg) {
  __shared__ float xt[64][133];
  const int b = blockIdx.x;
  const int t = threadIdx.x;
  if (b >= 4800) {   // border zero: 2244 border px * 16 uint4
    int tid = (b - 4800) * 256 + t;
    if (tid < (642*2 + 480*2) * 16) {
      int px = tid >> 4, q = tid & 15;
      int addr;
      if (px < 642) addr = px;
      else if (px < 1284) addr = 481*642 + (px - 642);
      else if (px < 1764) addr = (px - 1284 + 1) * 642;
      else addr = (px - 1764 + 1) * 642 + 641;
      ((uint4*)Timg)[(size_t)addr * 16 + q] = make_uint4(0u, 0u, 0u, 0u);
    }
    return;
  }
  const int h = b / 10, w0 = (b % 10) * 64;
  const int wl = t & 63, cib = t >> 6;
#pragma unroll
  for (int i = 0; i < 32; ++i) {
    int ci = cib + i*4;
    xt[wl][ci] = img[(size_t)ci*HWSZ + h*WW + w0 + wl];
  }
  __syncthreads();
  const int wp = t >> 2, c0 = (t & 3) * 32;
  u32 out[16];
#pragma unroll
  for (int j = 0; j < 16; ++j) {
    float a = xt[wp][c0 + 2*j], bb = xt[wp][c0 + 2*j + 1];
    out[j] = pack_bf16(a, bb);
  }
  u16* dst = Timg + ((size_t)(h+1)*TIMG_PAD_W + (w0 + 1 + wp)) * 128 + c0;
#pragma unroll
  for (int q = 0; q < 4; ++q)
    *(uint4*)(dst + q*8) = make_uint4(out[q*4], out[q*4+1], out[q*4+2], out[q*4+3]);
}

// ---------------- conv v5: LDS-staged, fragment-contiguous weights -------------
// block: 256 thr (4 waves), output 4 rows x 64 cols x 128 oc (256 px x 128 oc)
// wave: ocg = wv&1 (64 oc), rowg = wv>>1 (2 rows); acc 4x8 frags (128 px/wave)
#define REG_ROWS 6
#define REG_COLS 66
#define REG_PX (REG_ROWS*REG_COLS)   // 396
__launch_bounds__(256, 2)
__global__ void conv_mfma3_kernel(const u16* __restrict__ Timg,
                                  const u16* __restrict__ Wf,
                                  const float* __restrict__ ws,
                                  float* __restrict__ X) {
  __shared__ __align__(16) u16 reg_lds[REG_PX * 64];   // 50688 B
  const int b = blockIdx.x;
  const int h0 = (b / 10) * 4;
  const int w0 = (b % 10) * 64;
  const int t = threadIdx.x;
  const int wv = t >> 6, l = t & 63;
  const int n_lane = l & 15, k_lane = l >> 4;
  const int ocg = wv & 1;
  const int rowg = wv >> 1;

  f32x4 acc[4][8];
#pragma unroll
  for (int mt = 0; mt < 4; ++mt)
#pragma unroll
    for (int nt = 0; nt < 8; ++nt) acc[mt][nt] = (f32x4){0.f,0.f,0.f,0.f};

#pragma unroll 1
  for (int half = 0; half < 2; ++half) {
    const int ci0 = half * 64;
    __syncthreads();
    // stage 6 rows x 66 cols x 64 ci; phys 16B-unit j holds logical j^(c&7)
    for (int e = t; e < REG_PX * 8; e += 256) {
      int px = e >> 3, j = e & 7;
      int r = px / REG_COLS, c = px - r * REG_COLS;
      const u16* src = Timg + (size_t)(h0 + r) * (TIMG_PAD_W * 128)
                     + (w0 + c) * 128 + ci0 + ((j ^ (c & 7)) * 8);
      *(uint4*)((char*)reg_lds + px * 128 + j * 16) = *(const uint4*)src;
    }
    __syncthreads();
    const u16* wt = Wf + (((0*4 + half*2)*8) + ocg*4)*512 + l*8;  // tap 0 base
#pragma unroll 1
    for (int tap = 0; tap < 9; ++tap) {
      const int kh = (tap * 11) >> 5;       // tap/3
      const int kw = tap - kh * 3;
      const int swz = ((n_lane + kw) & 7) << 4;
      const int cb = n_lane + kw;
      const int rb = rowg*2 + kh;
      const u16* wtap = wt + tap * 16384;   // (tap*4)*8*512
#pragma unroll
      for (int s = 0; s < 2; ++s) {
        bf16x8 Af[4], Bf[8];
#pragma unroll
        for (int mt = 0; mt < 4; ++mt)
          Af[mt] = *(const bf16x8*)(wtap + s*4096 + mt*512);
#pragma unroll
        for (int nt = 0; nt < 8; ++nt) {
          int px = (rb + (nt >> 2)) * REG_COLS + cb + (nt & 3) * 16;
          Bf[nt] = *(const bf16x8*)((char*)reg_lds + px * 128
                                    + ((s*64 + k_lane*16) ^ swz));
        }
#pragma unroll
        for (int mt = 0; mt < 4; ++mt)
#pragma unroll
          for (int nt = 0; nt < 8; ++nt)
            acc[mt][nt] = __builtin_amdgcn_mfma_f32_16x16x32_bf16(Af[mt], Bf[nt], acc[mt][nt], 0, 0, 0);
      }
    }
  }
  // epilogue: bias + ReLU; D: col(px)=lane&15, row(oc)=k_lane*4+rr
  const float* bias = ws + OFF_BIAS2;
#pragma unroll
  for (int mt = 0; mt < 4; ++mt) {
    f32x4 bv = *(const f32x4*)(bias + ocg*64 + mt*16 + k_lane*4);
#pragma unroll
    for (int nt = 0; nt < 8; ++nt) {
      int row = h0 + rowg*2 + (nt >> 2);
      int col = w0 + (nt & 3)*16 + n_lane;
#pragma unroll
      for (int rr = 0; rr < 4; ++rr) {
        int oc = ocg*64 + mt*16 + k_lane*4 + rr;
        float v = acc[mt][nt][rr] + bv[rr];
        X[(size_t)oc * HWSZ + row*WW + col] = fmaxf(v, 0.f);
      }
    }
  }
}

// ---------------- fp32 fallback conv -------------------------------------------
__launch_bounds__(256)
__global__ void conv_kernel(const float* __restrict__ img,
                            const float* __restrict__ ws,
                            float* __restrict__ outX) {
  __shared__ __align__(16) float xs[8][10][20];
  __shared__ __align__(16) float wsm[8][9][64];
  const int b = blockIdx.x;
  const int oc0 = (b & 1) * 64;
  const int sidx = b >> 1;
  const int h0 = (sidx / 40) * 8;
  const int w0 = (sidx % 40) * 16;
  const int t = threadIdx.x;
  const int oc_t = t & 15;
  const int px_t = t >> 4;
  const int ph = px_t >> 1;
  const int pw0 = (px_t & 1) * 8;
  float acc[4][8];
#pragma unroll
  for (int o = 0; o < 4; o++)
#pragma unroll
    for (int m = 0; m < 8; m++) acc[o][m] = 0.f;
  const float* wT = ws + OFF_WT;
  for (int ci0 = 0; ci0 < 128; ci0 += 8) {
    __syncthreads();
    for (int e = t; e < 1440; e += 256) {
      int ci = e / 180; int rem = e - ci*180; int r = rem / 18; int cc2 = rem - r*18;
      int gh = h0 + r - 1, gw = w0 + cc2 - 1;
      float v = 0.f;
      if ((unsigned)gh < (unsigned)HH && (unsigned)gw < (unsigned)WW)
        v = img[(ci0+ci)*HWSZ + gh*WW + gw];
      xs[ci][r][cc2] = v;
    }
    for (int e = t; e < 4608; e += 256) {
      int oc = e & 63; int k = (e >> 6) % 9; int ci = e / 576;
      wsm[ci][k][oc] = wT[((ci0+ci)*9 + k)*128 + oc0 + oc];
    }
    __syncthreads();
#pragma unroll
    for (int ci = 0; ci < 8; ci++) {
#pragma unroll
      for (int kh = 0; kh < 3; kh++) {
        float x10[10];
        float4 xa = *(const float4*)&xs[ci][ph+kh][pw0];
        float4 xb = *(const float4*)&xs[ci][ph+kh][pw0+4];
        x10[0]=xa.x; x10[1]=xa.y; x10[2]=xa.z; x10[3]=xa.w;
        x10[4]=xb.x; x10[5]=xb.y; x10[6]=xb.z; x10[7]=xb.w;
        x10[8]=xs[ci][ph+kh][pw0+8]; x10[9]=xs[ci][ph+kh][pw0+9];
#pragma unroll
        for (int kw = 0; kw < 3; kw++) {
          float4 wv = *(const float4*)&wsm[ci][kh*3+kw][oc_t*4];
#pragma unroll
          for (int m = 0; m < 8; m++) {
            float xv = x10[kw+m];
            acc[0][m] += wv.x*xv; acc[1][m] += wv.y*xv;
            acc[2][m] += wv.z*xv; acc[3][m] += wv.w*xv;
          }
        }
      }
    }
  }
#pragma unroll
  for (int o = 0; o < 4; o++) {
    int oc = oc0 + oc_t*4 + o;
    float bias = ws[OFF_BIAS2 + oc];
    float4 r0, r1;
    r0.x = fmaxf(acc[o][0]+bias, 0.f); r0.y = fmaxf(acc[o][1]+bias, 0.f);
    r0.z = fmaxf(acc[o][2]+bias, 0.f); r0.w = fmaxf(acc[o][3]+bias, 0.f);
    r1.x = fmaxf(acc[o][4]+bias, 0.f); r1.y = fmaxf(acc[o][5]+bias, 0.f);
    r1.z = fmaxf(acc[o][6]+bias, 0.f); r1.w = fmaxf(acc[o][7]+bias, 0.f);
    float* dst = outX + (size_t)oc*HWSZ + (h0+ph)*WW + w0 + pw0;
    *(float4*)dst = r0; *(float4*)(dst+4) = r1;
  }
}

// ---------------- linear + ReLU -> Z -------------------------------------------
__launch_bounds__(256)
__global__ void linear_kernel(const float* __restrict__ pcd,
                              const float* __restrict__ ws,
                              const float* __restrict__ lin_b,
                              float* __restrict__ Z) {
  __shared__ __align__(16) float Mt[128][132];
  __shared__ __align__(16) float zs[16][132];
  const int b = blockIdx.x, t = threadIdx.x;
  const int n0 = b * 16;
#pragma unroll
  for (int i = 0; i < 16; i++) {
    int idx = t + i*256; int r = idx >> 5; int c4 = (idx & 31)*4;
    *(float4*)&Mt[r][c4] = *(const float4*)&ws[OFF_LWT + r*128 + c4];
  }
#pragma unroll
  for (int i = 0; i < 2; i++) {
    int idx = t + i*256; int r = idx >> 5; int c4 = (idx & 31)*4;
    *(float4*)&zs[r][c4] = *(const float4*)&pcd[(size_t)(n0+r)*128 + c4];
  }
  __syncthreads();
  const int nl = t & 15;
  const int c0 = (t >> 4) * 8;
  float acc[8];
#pragma unroll
  for (int q = 0; q < 8; q++) acc[q] = 0.f;
#pragma unroll 8
  for (int k = 0; k < 128; k++) {
    float z = zs[nl][k];
    float4 wa = *(const float4*)&Mt[k][c0];
    float4 wb = *(const float4*)&Mt[k][c0+4];
    acc[0]+=z*wa.x; acc[1]+=z*wa.y; acc[2]+=z*wa.z; acc[3]+=z*wa.w;
    acc[4]+=z*wb.x; acc[5]+=z*wb.y; acc[6]+=z*wb.z; acc[7]+=z*wb.w;
  }
  float4 ba = *(const float4*)&lin_b[c0];
  float4 bb = *(const float4*)&lin_b[c0+4];
  float4 r0, r1;
  r0.x = fmaxf(acc[0]+ba.x,0.f); r0.y = fmaxf(acc[1]+ba.y,0.f);
  r0.z = fmaxf(acc[2]+ba.z,0.f); r0.w = fmaxf(acc[3]+ba.w,0.f);
  r1.x = fmaxf(acc[4]+bb.x,0.f); r1.y = fmaxf(acc[5]+bb.y,0.f);
  r1.z = fmaxf(acc[6]+bb.z,0.f); r1.w = fmaxf(acc[7]+bb.w,0.f);
  float* dst = Z + (size_t)(n0+nl)*128 + c0;
  *(float4*)dst = r0; *(float4*)(dst+4) = r1;
}

// ---------------- pcd channel sums ---------------------------------------------
__launch_bounds__(256)
__global__ void sums_pcd_kernel(const float* __restrict__ Z, float* __restrict__ ws) {
  const int c = blockIdx.x, t = threadIdx.x;
  float s = 0.f;
  for (int n = t; n < NPC; n += 256) s += Z[(size_t)n*128 + c];
  __shared__ float red[256];
  red[t] = s; __syncthreads();
  for (int s2 = 128; s2 > 0; s2 >>= 1) { if (t < s2) red[t] += red[t+s2]; __syncthreads(); }
  if (t == 0) ws[OFF_SUMS_PCD + c] = red[0];
}

// ---------------- gram img via MFMA (bf16 LDS tile, fused channel sums) --------
__launch_bounds__(256)
__global__ void gram_img_mfma_kernel(const float* __restrict__ X,
                                     float* __restrict__ part,
                                     float* __restrict__ psums) {
  __shared__ __align__(16) u16 tile[128*64];   // [c][px64] bf16, XOR-swizzled
  const int b = blockIdx.x, t = threadIdx.x;
  const int px0 = b * CHUNK_I;
  const int pg = t & 15;
  const int g0 = t >> 4;
  const int wv = t >> 6, l = t & 63;
  const int i0 = (wv >> 1) * 64, j0 = (wv & 1) * 64;
  const int row16 = l & 15, kq = l >> 4;
  float csum[8];
#pragma unroll
  for (int q = 0; q < 8; ++q) csum[q] = 0.f;
  f32x4 acc[4][4];
#pragma unroll
  for (int a = 0; a < 4; ++a)
#pragma unroll
    for (int q = 0; q < 4; ++q) acc[a][q] = (f32x4){0.f,0.f,0.f,0.f};

  for (int ti = 0; ti < 19; ++ti) {
    const int plg = ti*64 + pg*4;
    float4 v[8];
    if (ti < 18) {
#pragma unroll
      for (int cc = 0; cc < 8; ++cc) {
        int c = g0 + cc*16;
        v[cc] = *(const float4*)(X + (size_t)c*HWSZ + px0 + plg);
      }
    } else {
#pragma unroll
      for (int cc = 0; cc < 8; ++cc) {
        int c = g0 + cc*16;
        const float* src = X + (size_t)c*HWSZ + px0;
#pragma unroll
        for (int j = 0; j < 4; ++j) {
          int p = plg + j;
          ((float*)&v[cc])[j] = (p < CHUNK_I) ? src[p] : 0.f;
        }
      }
    }
    __syncthreads();
#pragma unroll
    for (int cc = 0; cc < 8; ++cc) {
      int c = g0 + cc*16;
      csum[cc] += v[cc].x + v[cc].y + v[cc].z + v[cc].w;
      u32 w0 = pack_bf16(v[cc].x, v[cc].y);
      u32 w1 = pack_bf16(v[cc].z, v[cc].w);
      *(uint2*)((char*)tile + c*128 + ((pg*8) ^ ((c & 7) << 4))) = make_uint2(w0, w1);
    }
    __syncthreads();
#pragma unroll
    for (int f = 0; f < 2; ++f) {
      bf16x8 Af[4], Bf[4];
#pragma unroll
      for (int mt = 0; mt < 4; ++mt) {
        int c = i0 + mt*16 + row16;
        Af[mt] = *(const bf16x8*)((char*)tile + c*128 + ((f*64 + kq*16) ^ ((c & 7) << 4)));
      }
#pragma unroll
      for (int nt = 0; nt < 4; ++nt) {
        int c = j0 + nt*16 + row16;
        Bf[nt] = *(const bf16x8*)((char*)tile + c*128 + ((f*64 + kq*16) ^ ((c & 7) << 4)));
      }
#pragma unroll
      for (int mt = 0; mt < 4; ++mt)
#pragma unroll
        for (int nt = 0; nt < 4; ++nt)
          acc[mt][nt] = __builtin_amdgcn_mfma_f32_16x16x32_bf16(Af[mt], Bf[nt], acc[mt][nt], 0, 0, 0);
    }
  }
#pragma unroll
  for (int cc = 0; cc < 8; ++cc) {
    float s = csum[cc];
    s += __shfl_xor(s, 1, 64);
    s += __shfl_xor(s, 2, 64);
    s += __shfl_xor(s, 4, 64);
    s += __shfl_xor(s, 8, 64);
    if (pg == 0) psums[b*128 + g0 + cc*16] = s;
  }
  float* dst = part + (size_t)b*16384;
#pragma unroll
  for (int mt = 0; mt < 4; ++mt)
#pragma unroll
    for (int nt = 0; nt < 4; ++nt) {
#pragma unroll
      for (int r = 0; r < 4; ++r) {
        int i = i0 + mt*16 + kq*4 + r;
        int j = j0 + nt*16 + row16;
        dst[i*128 + j] = acc[mt][nt][r];
      }
    }
}

// ---------------- gram pcd (fp32) ----------------------------------------------
__launch_bounds__(256)
__global__ void gram_pcd_kernel(const float* __restrict__ Z, float* __restrict__ part) {
  __shared__ __align__(16) float zt[64][132];
  const int b = blockIdx.x, t = threadIdx.x;
  const int n0 = b * CHUNK_P;
  const int i0 = (t >> 4) * 8, j0 = (t & 15) * 8;
  float acc[8][8];
#pragma unroll
  for (int a = 0; a < 8; a++)
#pragma unroll
    for (int q = 0; q < 8; q++) acc[a][q] = 0.f;
  for (int tile = 0; tile < 6; tile++) {
    __syncthreads();
#pragma unroll
    for (int i = 0; i < 8; i++) {
      int idx = t + i*256; int r = idx >> 5; int c4 = (idx & 31)*4;
      int lrow = tile*64 + r;
      int n = n0 + lrow;
      float4 v = {0.f,0.f,0.f,0.f};
      if (lrow < CHUNK_P && n < NPC) v = *(const float4*)&Z[(size_t)n*128 + c4];
      *(float4*)&zt[r][c4] = v;
    }
    __syncthreads();
#pragma unroll 4
    for (int n = 0; n < 64; n++) {
      float4 a0 = *(const float4*)&zt[n][i0];
      float4 a1 = *(const float4*)&zt[n][i0+4];
      float4 b0 = *(const float4*)&zt[n][j0];
      float4 b1 = *(const float4*)&zt[n][j0+4];
      float av[8] = {a0.x,a0.y,a0.z,a0.w,a1.x,a1.y,a1.z,a1.w};
      float bv[8] = {b0.x,b0.y,b0.z,b0.w,b1.x,b1.y,b1.z,b1.w};
#pragma unroll
      for (int a = 0; a < 8; a++)
#pragma unroll
        for (int q = 0; q < 8; q++) acc[a][q] += av[a]*bv[q];
    }
  }
  float* dst = part + (size_t)b*16384;
#pragma unroll
  for (int a = 0; a < 8; a++) {
    float4 w0v = {acc[a][0],acc[a][1],acc[a][2],acc[a][3]};
    float4 w1v = {acc[a][4],acc[a][5],acc[a][6],acc[a][7]};
    *(float4*)&dst[(i0+a)*128 + j0] = w0v;
    *(float4*)&dst[(i0+a)*128 + j0 + 4] = w1v;
  }
}

// ---------------- reduce partials -> cov (img channel sums fused) --------------
__launch_bounds__(128)
__global__ void reduce_cov_kernel(float* __restrict__ ws) {
  const int b = blockIdx.x, t = threadIdx.x;
  const bool isimg = (b < 128);
  const int i = isimg ? b : b - 128;
  const int nparts = isimg ? NBI : NBP;
  const float* part = ws + (isimg ? OFF_PART_IMG : OFF_PART_PCD);
  __shared__ float sums[128];
  if (isimg) {
    const float* ps = ws + OFF_PSUMS;
    float s = 0.f;
    for (int p = 0; p < NBI; ++p) s += ps[p*128 + t];
    sums[t] = s;
  } else {
    sums[t] = ws[OFF_SUMS_PCD + t];
  }
  __syncthreads();
  float g = 0.f;
  for (int p = 0; p < nparts; p++) g += part[(size_t)p*16384 + i*128 + t];
  float Si = sums[i];
  float Sj = sums[t];
  float n = isimg ? (float)HWSZ : (float)NPC;
  float cov = (g - Si*Sj/n) / (n - 1.f);
  ws[(isimg ? OFF_COV_IMG : OFF_COV_PCD) + i*128 + t] = cov;
}

// ---------------- in-place Gauss-Jordan inverse, 2 barriers/iter ---------------
__launch_bounds__(512)
__global__ void invert_kernel(float* __restrict__ ws) {
  __shared__ __align__(16) float A[128][132];
  const int b = blockIdx.x, t = threadIdx.x;
  const float* src = ws + (b == 0 ? OFF_COV_IMG : OFF_COV_PCD);
  float* dst = ws + (b == 0 ? OFF_INV_IMG : OFF_INV_PCD);
  for (int i = 0; i < 32; i++) {
    int idx = t + i*512; int r = idx >> 7; int cc = idx & 127;
    A[r][cc] = src[idx] + (r == cc ? 1e-6f : 0.f);
  }
  const int row = t >> 2;
  const int cb = (t & 3) * 32;
  for (int k = 0; k < 128; k++) {
    __syncthreads();
    float ip = 1.f / A[k][k];
    float f = A[row][k];
    float4 p[8];
#pragma unroll
    for (int j = 0; j < 8; ++j) p[j] = *(const float4*)&A[k][cb + j*4];
    __syncthreads();
    if (row == k) {
#pragma unroll
      for (int j = 0; j < 8; ++j) {
        int c4 = cb + j*4;
        float4 v;
        v.x = (c4   == k) ? ip : p[j].x * ip;
        v.y = (c4+1 == k) ? ip : p[j].y * ip;
        v.z = (c4+2 == k) ? ip : p[j].z * ip;
        v.w = (c4+3 == k) ? ip : p[j].w * ip;
        *(float4*)&A[k][c4] = v;
      }
    } else {
      float g = f * ip;
#pragma unroll
      for (int j = 0; j < 8; ++j) {
        int c4 = cb + j*4;
        float4 v = *(const float4*)&A[row][c4];
        v.x -= g*p[j].x; v.y -= g*p[j].y; v.z -= g*p[j].z; v.w -= g*p[j].w;
        if (k >= c4 && k < c4+4) {
          if (k == c4) v.x = -g; else if (k == c4+1) v.y = -g;
          else if (k == c4+2) v.z = -g; else v.w = -g;
        }
        *(float4*)&A[row][c4] = v;
      }
    }
  }
  __syncthreads();
  for (int i = 0; i < 32; i++) {
    int idx = t + i*512; int r = idx >> 7; int cc = idx & 127;
    dst[idx] = A[r][cc];
  }
}

// ---------------- attention rows -> transposed mix matrices M^T ----------------
// cov and inv are symmetric: read mat[k][j] (coalesced) instead of mat[j][k]
__launch_bounds__(128)
__global__ void attn_kernel(float* __restrict__ ws) {
  const int b = blockIdx.x, j = threadIdx.x;
  const bool isimg = (b < 128);
  const int i = isimg ? b : b - 128;
  const float* rowA = ws + (isimg ? OFF_COV_PCD : OFF_COV_IMG) + i*128;
  const float* matA = ws + (isimg ? OFF_INV_IMG : OFF_INV_PCD);
  const float* rowB = ws + (isimg ? OFF_COV_IMG : OFF_COV_PCD) + i*128;
  const float* matB = ws + (isimg ? OFF_COV_IMG : OFF_COV_PCD);
  __shared__ float rA[128], rB[128], red[128];
  rA[j] = rowA[j]; rB[j] = rowB[j];
  __syncthreads();
  float dA = 0.f, dB = 0.f;
#pragma unroll 8
  for (int k = 0; k < 128; ++k) {
    dA += rA[k] * matA[k*128 + j];
    dB += rB[k] * matB[k*128 + j];
  }
  dA *= 0.0078125f; dB *= 0.0078125f;
  red[j] = dA; __syncthreads();
  for (int s2 = 64; s2 > 0; s2 >>= 1) { if (j < s2) red[j] = fmaxf(red[j], red[j+s2]); __syncthreads(); }
  float mA = red[0]; __syncthreads();
  float eA = expf(dA - mA);
  red[j] = eA; __syncthreads();
  for (int s2 = 64; s2 > 0; s2 >>= 1) { if (j < s2) red[j] += red[j+s2]; __syncthreads(); }
  float sA = red[0]; __syncthreads();
  red[j] = dB; __syncthreads();
  for (int s2 = 64; s2 > 0; s2 >>= 1) { if (j < s2) red[j] = fmaxf(red[j], red[j+s2]); __syncthreads(); }
  float mB = red[0]; __syncthreads();
  float eB = expf(dB - mB);
  red[j] = eB; __syncthreads();
  for (int s2 = 64; s2 > 0; s2 >>= 1) { if (j < s2) red[j] += red[j+s2]; __syncthreads(); }
  float sB = red[0]; __syncthreads();
  float m = 0.1f * (eA/sA + eB/sB);
  float* MT = ws + (isimg ? OFF_MT_IMG : OFF_MT_PCD);
  MT[j*128 + i] = m;
}

// ---------------- M_img -> bf16 fragment layout (fid = f*8 + ob) ---------------
__global__ void mb_kernel(float* __restrict__ ws) {
  int e = blockIdx.x * 256 + threadIdx.x;   // 16384
  int j = e & 7, l = (e >> 3) & 63, ob = (e >> 9) & 7, f = (e >> 12) & 3;
  int c = ob*16 + (l & 15);
  int k = f*32 + ((l >> 4) & 3)*8 + j;
  ((u16*)(ws + OFF_MB))[e] = to_bf16(ws[OFF_MT_IMG + k*128 + c]);
}

// ---------------- img final via MFMA + coalesced epilogue ----------------------
#define IF_PAD 132
__launch_bounds__(256, 2)
__global__ void img_final_mfma_kernel(const float* __restrict__ img_in,
                                      const float* __restrict__ ws,
                                      float* __restrict__ io) {
  __shared__ __align__(16) char smem[128 * IF_PAD * 4];   // 67584 B
  u16* bt = (u16*)smem;          // phase 1: [px][c] bf16, XOR-swizzled (32 KB)
  float* ts = (float*)smem;      // phase 3: [c][IF_PAD] fp32
  const int blk = blockIdx.x, t = threadIdx.x;
  const int px0 = blk * 128;
  const int pxg = (t & 31) * 4;
  const int cp0 = t >> 5;
#pragma unroll
  for (int cc = 0; cc < 8; ++cc) {
    int cpair = cp0 + cc*8;
    const float* s0 = io + (size_t)(2*cpair)*HWSZ + px0 + pxg;
    float4 a = *(const float4*)s0;
    float4 b4 = *(const float4*)(s0 + HWSZ);
#pragma unroll
    for (int j = 0; j < 4; ++j) {
      int pxl = pxg + j;
      *(u32*)((char*)bt + pxl*256 + ((cpair*4) ^ ((pxl & 7) << 4))) =
          pack_bf16(((const float*)&a)[j], ((const float*)&b4)[j]);
    }
  }
  __syncthreads();
  const int wv = t >> 6, l = t & 63;
  const int i0 = (wv >> 1) * 64, j0 = (wv & 1) * 64;
  const int row16 = l & 15, kq = l >> 4;
  const u16* Mbf = (const u16*)(ws + OFF_MB);
  f32x4 acc[4][4];
#pragma unroll
  for (int a = 0; a < 4; ++a)
#pragma unroll
    for (int q = 0; q < 4; ++q) acc[a][q] = (f32x4){0.f,0.f,0.f,0.f};
#pragma unroll
  for (int f = 0; f < 4; ++f) {
    bf16x8 Bf[4], Am[4];
#pragma unroll
    for (int nt = 0; nt < 4; ++nt) {
      int pxl = j0 + nt*16 + row16;
      Bf[nt] = *(const bf16x8*)((char*)bt + pxl*256 + ((f*64 + kq*16) ^ ((pxl & 7) << 4)));
    }
#pragma unroll
    for (int mt = 0; mt < 4; ++mt) {
      int ob = (wv >> 1) * 4 + mt;
      Am[mt] = *(const bf16x8*)(Mbf + (f*8 + ob)*512 + l*8);
    }
#pragma unroll
    for (int mt = 0; mt < 4; ++mt)
#pragma unroll
      for (int nt = 0; nt < 4; ++nt)
        acc[mt][nt] = __builtin_amdgcn_mfma_f32_16x16x32_bf16(Am[mt], Bf[nt], acc[mt][nt], 0, 0, 0);
  }
  __syncthreads();   // bt no longer needed
#pragma unroll
  for (int mt = 0; mt < 4; ++mt)
#pragma unroll
    for (int nt = 0; nt < 4; ++nt) {
      int pxl = j0 + nt*16 + row16;
#pragma unroll
      for (int r = 0; r < 4; ++r) {
        int c = i0 + mt*16 + kq*4 + r;
        ts[c*IF_PAD + pxl] = acc[mt][nt][r];
      }
    }
  __syncthreads();
  const int c = t >> 1, ph = (t & 1) * 64;
#pragma unroll
  for (int j = 0; j < 16; ++j) {
    int px = ph + j*4;
    float4 v = *(const float4*)&ts[c*IF_PAD + px];
    size_t off = (size_t)c*HWSZ + px0 + px;
    float4 o = *(const float4*)&img_in[off];
    float4 r;
    r.x = v.x + 0.8f*o.x; r.y = v.y + 0.8f*o.y;
    r.z = v.z + 0.8f*o.z; r.w = v.w + 0.8f*o.w;
    *(float4*)&io[off] = r;
  }
}

// ---------------- pcd final: Z = Z @ M_pcd^T + 0.8*pcd (in place) --------------
__launch_bounds__(256)
__global__ void pcd_final_kernel(const float* __restrict__ pcd_in,
                                 const float* __restrict__ ws,
                                 float* __restrict__ Z) {
  __shared__ __align__(16) float Mt[128][132];
  __shared__ __align__(16) float zs[16][132];
  const int b = blockIdx.x, t = threadIdx.x;
  const int n0 = b * 16;
#pragma unroll
  for (int i = 0; i < 16; i++) {
    int idx = t + i*256; int r = idx >> 5; int c4 = (idx & 31)*4;
    *(float4*)&Mt[r][c4] = *(const float4*)&ws[OFF_MT_PCD + r*128 + c4];
  }
#pragma unroll
  for (int i = 0; i < 2; i++) {
    int idx = t + i*256; int r = idx >> 5; int c4 = (idx & 31)*4;
    *(float4*)&zs[r][c4] = *(const float4*)&Z[(size_t)(n0+r)*128 + c4];
  }
  __syncthreads();
  const int nl = t & 15;
  const int c0 = (t >> 4) * 8;
  float acc[8];
#pragma unroll
  for (int q = 0; q < 8; q++) acc[q] = 0.f;
#pragma unroll 8
  for (int k = 0; k < 128; k++) {
    float z = zs[nl][k];
    float4 wa = *(const float4*)&Mt[k][c0];
    float4 wb = *(const float4*)&Mt[k][c0+4];
    acc[0]+=z*wa.x; acc[1]+=z*wa.y; acc[2]+=z*wa.z; acc[3]+=z*wa.w;
    acc[4]+=z*wb.x; acc[5]+=z*wb.y; acc[6]+=z*wb.z; acc[7]+=z*wb.w;
  }
  size_t off = (size_t)(n0+nl)*128 + c0;
  float4 pa = *(const float4*)&pcd_in[off];
  float4 pb = *(const float4*)&pcd_in[off+4];
  float4 r0, r1;
  r0.x = acc[0] + 0.8f*pa.x; r0.y = acc[1] + 0.8f*pa.y;
  r0.z = acc[2] + 0.8f*pa.z; r0.w = acc[3] + 0.8f*pa.w;
  r1.x = acc[4] + 0.8f*pb.x; r1.y = acc[5] + 0.8f*pb.y;
  r1.z = acc[6] + 0.8f*pb.z; r1.w = acc[7] + 0.8f*pb.w;
  *(float4*)&Z[off] = r0; *(float4*)&Z[off+4] = r1;
}

extern "C" void kernel_launch(void* const* d_in, const int* in_sizes, int n_in,
                              void* d_out, int out_size, void* d_ws, size_t ws_size,
                              hipStream_t stream) {
  (void)in_sizes; (void)n_in; (void)out_size;
  const float* img_in = (const float*)d_in[0];
  const float* pcd_in = (const float*)d_in[1];
  const float* conv_w = (const float*)d_in[2];
  const float* conv_b = (const float*)d_in[3];
  const float* gamma  = (const float*)d_in[4];
  const float* beta   = (const float*)d_in[5];
  const float* mean   = (const float*)d_in[6];
  const float* var    = (const float*)d_in[7];
  const float* lin_w  = (const float*)d_in[8];
  const float* lin_b  = (const float*)d_in[9];
  float* out = (float*)d_out;
  float* X = out;            // [128][307200] conv output, transformed in place
  float* Z = out + IMG_SZ;   // [22432][128] linear output, transformed in place
  float* ws = (float*)d_ws;
  const int big = (ws_size >= (size_t)WS_NEED_FLOATS * 4) ? 1 : 0;

  hipLaunchKernelGGL(prep_kernel, dim3(64), dim3(256), 0, stream,
                     conv_w, conv_b, gamma, beta, mean, var, lin_w, ws, big);
  if (big) {
    u16* Timg = (u16*)(ws + OFF_TIMG_F);
    u16* Wf = (u16*)(ws + OFF_WB);
    hipLaunchKernelGGL(timg_kernel, dim3(4941), dim3(256), 0, stream, img_in, Timg);
    hipLaunchKernelGGL(conv_mfma3_kernel, dim3(1200), dim3(256), 0, stream, Timg, Wf, ws, X);
  } else {
    hipLaunchKernelGGL(conv_kernel, dim3(4800), dim3(256), 0, stream, img_in, ws, X);
  }
  hipLaunchKernelGGL(linear_kernel, dim3(NPC/16), dim3(256), 0, stream, pcd_in, ws, lin_b, Z);
  hipLaunchKernelGGL(gram_img_mfma_kernel, dim3(NBI), dim3(256), 0, stream,
                     X, ws + OFF_PART_IMG, ws + OFF_PSUMS);
  hipLaunchKernelGGL(sums_pcd_kernel, dim3(128), dim3(256), 0, stream, Z, ws);
  hipLaunchKernelGGL(gram_pcd_kernel, dim3(NBP), dim3(256), 0, stream, Z, ws + OFF_PART_PCD);
  hipLaunchKernelGGL(reduce_cov_kernel, dim3(256), dim3(128), 0, stream, ws);
  hipLaunchKernelGGL(invert_kernel, dim3(2), dim3(512), 0, stream, ws);
  hipLaunchKernelGGL(attn_kernel, dim3(256), dim3(128), 0, stream, ws);
  hipLaunchKernelGGL(mb_kernel, dim3(64), dim3(256), 0, stream, ws);
  hipLaunchKernelGGL(img_final_mfma_kernel, dim3(HWSZ/128), dim3(256), 0, stream, img_in, ws, X);
  hipLaunchKernelGGL(pcd_final_kernel, dim3(NPC/16), dim3(256), 0, stream, pcd_in, ws, Z);
}